// Round 6
// baseline (666.024 us; speedup 1.0000x reference)
//
#include <hip/hip_runtime.h>
#include <math.h>

#define HWSZ 16384

typedef __attribute__((ext_vector_type(8))) short short8;
typedef __attribute__((ext_vector_type(8))) unsigned short ush8;
typedef __attribute__((ext_vector_type(4))) float f4;
typedef __attribute__((ext_vector_type(16))) float f16x;

__device__ __forceinline__ ushort f2bf(float f) {
    unsigned u = __float_as_uint(f);
    return (ushort)((u + 0x7fffu + ((u >> 16) & 1u)) >> 16);
}
__device__ __forceinline__ float bf2f(ushort b) {
    return __uint_as_float(((unsigned)b) << 16);
}

// ---------------- weight prep ----------------
__global__ void k_prep_w2(const float* __restrict__ w, float* __restrict__ wt) {
    int idx = blockIdx.x * 256 + threadIdx.x;        // 1152*16
    if (idx >= 1152 * 16) return;
    int k = idx >> 4, oc = idx & 15;
    wt[idx] = (oc < 10) ? w[oc * 1152 + k] : 0.f;
}
// w_shared [oc][c][kh][kw] -> [oc][tap][c] bf16 hi/lo
__global__ void k_cvt_w(const float* __restrict__ w, ushort* __restrict__ wh,
                        ushort* __restrict__ wl) {
    int idx = blockIdx.x * 256 + threadIdx.x;   // 589824
    if (idx >= 589824) return;
    int oc = idx / 4608, r = idx - oc * 4608;
    int tap = r >> 9, c = r & 511;
    float f = w[oc * 4608 + c * 9 + tap];
    ushort hb = f2bf(f);
    wh[idx] = hb;
    wl[idx] = f2bf(f - bf2f(hb));
}
// x [c][hw] fp32 -> xt_hi/xt_lo [hw][c] bf16
__global__ __launch_bounds__(256) void k_cvt_x(const float* __restrict__ x,
        ushort* __restrict__ xh, ushort* __restrict__ xl) {
    __shared__ float T[64 * 65];
    int hw0 = blockIdx.x << 6;
    int c0 = blockIdx.y << 6;
    int t = threadIdx.x;
    {
        int cl = t >> 2, q = t & 3;
        const float* src = x + (size_t)(c0 + cl) * HWSZ + hw0 + q * 16;
        #pragma unroll
        for (int k = 0; k < 4; k++) {
            float4 v = *reinterpret_cast<const float4*>(src + k * 4);
            float* dst = &T[cl * 65 + q * 16 + k * 4];
            dst[0] = v.x; dst[1] = v.y; dst[2] = v.z; dst[3] = v.w;
        }
    }
    __syncthreads();
    {
        int hwl = t >> 2, q = t & 3;
        int cc = q * 16;
        size_t ob = (size_t)(hw0 + hwl) * 512 + c0 + cc;
        #pragma unroll
        for (int half = 0; half < 2; half++) {
            ush8 hv, lv;
            #pragma unroll
            for (int k = 0; k < 8; k++) {
                float f = T[(cc + half * 8 + k) * 65 + hwl];
                ushort hb = f2bf(f);
                hv[k] = hb;
                lv[k] = f2bf(f - bf2f(hb));
            }
            *reinterpret_cast<ush8*>(xh + ob + half * 8) = hv;
            *reinterpret_cast<ush8*>(xl + ob + half * 8) = lv;
        }
    }
}

// ---------------- conv1 via 32x32x16 MFMA, 128x128 tile, K-split 2 ----------------
// grid (128 rows x 2 ksplit); block 256 = 4 waves in 2x2; wave tile 64px x 64oc.
// Writes fp32 partials part[kidx][hw][oc].
__global__ __launch_bounds__(256) void k_conv1_mfma(
        const ushort* __restrict__ xh, const ushort* __restrict__ xl,
        const ushort* __restrict__ wh, const ushort* __restrict__ wl,
        float* __restrict__ part) {
    __shared__ ushort smem[20480];   // 40960 B: [buf][Ahi|Alo|Bhi|Blo][128][20]
    const int t = threadIdx.x;
    const int h = blockIdx.x >> 1, kidx = blockIdx.x & 1;
    const int l = t & 63, wid = t >> 6;
    const int wm = wid >> 1, wn = wid & 1;
    const int l31 = l & 31, lk = l >> 5;
    const int srow = t >> 1, skh = t & 1;
    const int cbase0 = kidx * 256;

    f16x acc[2][2];
    #pragma unroll
    for (int m = 0; m < 2; m++)
        #pragma unroll
        for (int n = 0; n < 2; n++)
            #pragma unroll
            for (int i = 0; i < 16; i++) acc[m][n][i] = 0.f;

    short8 rA[2], rB[2];
    const short8 zz = {0, 0, 0, 0, 0, 0, 0, 0};

    auto issue = [&](int it) {
        int kc = it / 9, tap = it - kc * 9;
        int dh = tap / 3 - 1, dw = tap - (tap / 3) * 3 - 1;
        int cb = cbase0 + kc * 16 + skh * 8;
        int hh = h + dh, wwp = srow + dw;
        if (((unsigned)hh < 128u) & ((unsigned)wwp < 128u)) {
            size_t off = ((size_t)(hh * 128 + wwp) << 9) + cb;
            rA[0] = *reinterpret_cast<const short8*>(xh + off);
            rA[1] = *reinterpret_cast<const short8*>(xl + off);
        } else { rA[0] = zz; rA[1] = zz; }
        size_t ob = (size_t)srow * 4608 + tap * 512 + cb;
        rB[0] = *reinterpret_cast<const short8*>(wh + ob);
        rB[1] = *reinterpret_cast<const short8*>(wl + ob);
    };
    auto wstage = [&](int buf) {
        int a = srow * 20 + skh * 8;
        ushort* s = smem + buf * 10240;
        *reinterpret_cast<short8*>(s + a) = rA[0];
        *reinterpret_cast<short8*>(s + 2560 + a) = rA[1];
        *reinterpret_cast<short8*>(s + 5120 + a) = rB[0];
        *reinterpret_cast<short8*>(s + 7680 + a) = rB[1];
    };

    issue(0);
    wstage(0);
    issue(1);
    __syncthreads();

    for (int it = 0; it < 144; ++it) {
        int buf = it & 1;
        const ushort* s = smem + buf * 10240;
        short8 aH[2], aL[2], bH[2], bL[2];
        #pragma unroll
        for (int m = 0; m < 2; m++) {
            int ra = (wm * 64 + m * 32 + l31) * 20 + lk * 8;
            aH[m] = *reinterpret_cast<const short8*>(s + ra);
            aL[m] = *reinterpret_cast<const short8*>(s + 2560 + ra);
        }
        #pragma unroll
        for (int n = 0; n < 2; n++) {
            int rb = (wn * 64 + n * 32 + l31) * 20 + lk * 8;
            bH[n] = *reinterpret_cast<const short8*>(s + 5120 + rb);
            bL[n] = *reinterpret_cast<const short8*>(s + 7680 + rb);
        }
        #pragma unroll
        for (int m = 0; m < 2; m++)
            #pragma unroll
            for (int n = 0; n < 2; n++) {
                acc[m][n] = __builtin_amdgcn_mfma_f32_32x32x16_bf16(aH[m], bH[n], acc[m][n], 0, 0, 0);
                acc[m][n] = __builtin_amdgcn_mfma_f32_32x32x16_bf16(aL[m], bH[n], acc[m][n], 0, 0, 0);
                acc[m][n] = __builtin_amdgcn_mfma_f32_32x32x16_bf16(aH[m], bL[n], acc[m][n], 0, 0, 0);
            }
        if (it + 1 < 144) {
            wstage(buf ^ 1);
            if (it + 2 < 144) issue(it + 2);
        }
        __syncthreads();
    }

    // epilogue: direct fp32 partial store, [hw][oc] layout
    float* pb = part + ((size_t)kidx << 21);
    #pragma unroll
    for (int m = 0; m < 2; m++)
        #pragma unroll
        for (int n = 0; n < 2; n++) {
            int oc = wn * 64 + n * 32 + l31;
            #pragma unroll
            for (int r = 0; r < 16; r++) {
                int px = wm * 64 + m * 32 + (r & 3) + ((r >> 2) << 3) + (lk << 2);
                pb[(size_t)(h * 128 + px) * 128 + oc] = acc[m][n][r];
            }
        }
}

// combine partials + bias + relu, transpose [hw][oc] -> [oc][hw]
__global__ __launch_bounds__(256) void k_conv1_fin(const float* __restrict__ part,
        const float* __restrict__ bias, float* __restrict__ out) {
    __shared__ float T[128 * 65];
    int hw0 = blockIdx.x << 6;
    int t = threadIdx.x;
    const float* p0 = part;
    const float* p1 = part + (1u << 21);
    #pragma unroll
    for (int k = 0; k < 8; k++) {
        int fl = (t + k * 256) * 4;
        int hwl = fl >> 7, oc0 = fl & 127;
        size_t o = (size_t)(hw0 + hwl) * 128 + oc0;
        float4 a = *reinterpret_cast<const float4*>(p0 + o);
        float4 b = *reinterpret_cast<const float4*>(p1 + o);
        T[(oc0 + 0) * 65 + hwl] = a.x + b.x;
        T[(oc0 + 1) * 65 + hwl] = a.y + b.y;
        T[(oc0 + 2) * 65 + hwl] = a.z + b.z;
        T[(oc0 + 3) * 65 + hwl] = a.w + b.w;
    }
    __syncthreads();
    #pragma unroll
    for (int k = 0; k < 8; k++) {
        int fl = (t + k * 256) * 4;
        int oc = fl >> 6, c = fl & 63;
        float b = bias[oc];
        float4 v;
        v.x = fmaxf(T[oc * 65 + c + 0] + b, 0.f);
        v.y = fmaxf(T[oc * 65 + c + 1] + b, 0.f);
        v.z = fmaxf(T[oc * 65 + c + 2] + b, 0.f);
        v.w = fmaxf(T[oc * 65 + c + 3] + b, 0.f);
        *reinterpret_cast<float4*>(out + (size_t)oc * HWSZ + hw0 + c) = v;
    }
}

// ---------------- conv2: 128->10(pad16) 3x3 + bias + sigmoid ----------------
__global__ __launch_bounds__(256) void k_conv2(const float* __restrict__ lidar,
        const float* __restrict__ wt, const float* __restrict__ bias,
        float* __restrict__ sig) {
    __shared__ float xs[16 * 3 * 68];
    __shared__ float wsm[144 * 16];
    int bid = blockIdx.x;
    int h = bid >> 1, w0 = (bid & 1) << 6;
    int t = threadIdx.x;
    int tpx = (t & 15) << 2;
    int oc = t >> 4;                // 0..15 (10 real)
    float acc[4] = {0.f, 0.f, 0.f, 0.f};
    for (int c0 = 0; c0 < 128; c0 += 16) {
        for (int i = t; i < 16 * 3 * 66; i += 256) {
            int c = i / 198; int rem = i - c * 198; int r = rem / 66; int j = rem - r * 66;
            int gr = h - 1 + r, gc = w0 - 1 + j;
            float v = 0.f;
            if (((unsigned)gr < 128u) & ((unsigned)gc < 128u))
                v = lidar[(c0 + c) * HWSZ + gr * 128 + gc];
            xs[(c * 3 + r) * 68 + j] = v;
        }
        {
            const float4* src = (const float4*)(wt + c0 * 9 * 16);
            float4* dst = (float4*)wsm;
            for (int i = t; i < 576; i += 256) dst[i] = src[i];
        }
        __syncthreads();
        #pragma unroll 4
        for (int c = 0; c < 16; c++) {
            #pragma unroll
            for (int kh = 0; kh < 3; kh++) {
                const float* xr = &xs[(c * 3 + kh) * 68 + tpx];
                float xv0 = xr[0], xv1 = xr[1], xv2 = xr[2], xv3 = xr[3], xv4 = xr[4], xv5 = xr[5];
                #pragma unroll
                for (int kw = 0; kw < 3; kw++) {
                    float wv = wsm[(c * 9 + kh * 3 + kw) * 16 + oc];
                    float p0 = (kw == 0) ? xv0 : ((kw == 1) ? xv1 : xv2);
                    float p1 = (kw == 0) ? xv1 : ((kw == 1) ? xv2 : xv3);
                    float p2 = (kw == 0) ? xv2 : ((kw == 1) ? xv3 : xv4);
                    float p3 = (kw == 0) ? xv3 : ((kw == 1) ? xv4 : xv5);
                    acc[0] += p0 * wv; acc[1] += p1 * wv; acc[2] += p2 * wv; acc[3] += p3 * wv;
                }
            }
        }
        __syncthreads();
    }
    if (oc < 10) {
        float b = bias[oc];
        int col = h * 128 + w0 + tpx;
        float4 v;
        v.x = 1.f / (1.f + expf(-(acc[0] + b)));
        v.y = 1.f / (1.f + expf(-(acc[1] + b)));
        v.z = 1.f / (1.f + expf(-(acc[2] + b)));
        v.w = 1.f / (1.f + expf(-(acc[3] + b)));
        *(float4*)&sig[oc * HWSZ + col] = v;
    }
}

// ---------------- 3x3 local-max NMS ----------------
__global__ void k_nms(const float* __restrict__ sig, float* __restrict__ hm) {
    int gid = blockIdx.x * 256 + threadIdx.x;   // 163840
    int c = gid >> 14, i = gid & 16383;
    int h = i >> 7, w = i & 127;
    float v = sig[gid];
    float keep = 0.f;
    if (c >= 8) keep = v;
    else if (h >= 1 && h <= 126 && w >= 1 && w <= 126) {
        const float* s = sig + c * HWSZ;
        float m = v;
        #pragma unroll
        for (int dh = -1; dh <= 1; dh++)
            #pragma unroll
            for (int dw = -1; dw <= 1; dw++)
                m = fmaxf(m, s[(h + dh) * 128 + (w + dw)]);
        keep = (v == m) ? v : 0.f;
    }
    hm[gid] = keep;
}

// ---------------- exact top-200 radix select ----------------
__global__ void k_hist_hi(const float* __restrict__ hm, unsigned* __restrict__ hist) {
    int gid = blockIdx.x * 256 + threadIdx.x;
    unsigned k = __float_as_uint(hm[gid]);
    if (k) atomicAdd(&hist[k >> 16], 1u);
}
__global__ void k_scan_hi(const unsigned* __restrict__ hist, unsigned* __restrict__ state) {
    __shared__ unsigned ps[256];
    __shared__ int selc;
    __shared__ unsigned selcum;
    __shared__ unsigned cb[256];
    int t = threadIdx.x;
    unsigned s = 0;
    const unsigned* hp = hist + t * 256;
    for (int i = 0; i < 256; i++) s += hp[i];
    ps[t] = s;
    __syncthreads();
    if (t == 0) {
        unsigned cum = 0; int c = 255;
        for (; c > 0; c--) { if (cum + ps[c] >= 200u) break; cum += ps[c]; }
        selc = c; selcum = cum;
    }
    __syncthreads();
    int c = selc;
    cb[t] = hist[c * 256 + t];
    __syncthreads();
    if (t == 0) {
        unsigned cum = selcum; int b = 255;
        for (; b > 0; b--) { if (cum + cb[b] >= 200u) break; cum += cb[b]; }
        state[8] = (unsigned)(c * 256 + b);   // b*
        state[9] = 200u - cum;                // K'
        state[10] = cum;                      // count strictly above bin b*
    }
}
__global__ void k_hist_lo(const float* __restrict__ hm, const unsigned* __restrict__ state,
                          unsigned* __restrict__ hist) {
    int gid = blockIdx.x * 256 + threadIdx.x;
    unsigned k = __float_as_uint(hm[gid]);
    if (k && (k >> 16) == state[8]) atomicAdd(&hist[k & 0xFFFFu], 1u);
}
__global__ void k_scan_lo(const unsigned* __restrict__ hist, unsigned* __restrict__ state) {
    __shared__ unsigned ps[256];
    __shared__ int selc;
    __shared__ unsigned selcum;
    __shared__ unsigned cb[256];
    int t = threadIdx.x;
    unsigned target = state[9];
    unsigned s = 0;
    const unsigned* hp = hist + t * 256;
    for (int i = 0; i < 256; i++) s += hp[i];
    ps[t] = s;
    __syncthreads();
    if (t == 0) {
        unsigned cum = 0; int c = 255;
        for (; c > 0; c--) { if (cum + ps[c] >= target) break; cum += ps[c]; }
        selc = c; selcum = cum;
    }
    __syncthreads();
    int c = selc;
    cb[t] = hist[c * 256 + t];
    __syncthreads();
    if (t == 0) {
        unsigned cum = selcum; int b = 255;
        for (; b > 0; b--) { if (cum + cb[b] >= target) break; cum += cb[b]; }
        unsigned lstar = (unsigned)(c * 256 + b);
        state[2] = (state[8] << 16) | lstar;  // key*
        state[0] = state[10] + cum;           // C_gt
        state[1] = target - cum;              // need_eq ties
    }
}
__global__ void k_collect(const float* __restrict__ hm, const unsigned* __restrict__ state,
        unsigned* __restrict__ ck, unsigned* __restrict__ ci,
        unsigned* __restrict__ ti, unsigned* __restrict__ cnts) {
    int gid = blockIdx.x * 256 + threadIdx.x;
    unsigned k = __float_as_uint(hm[gid]);
    unsigned ks = state[2];
    if (k > ks) {
        unsigned pos = atomicAdd(&cnts[0], 1u);
        if (pos < 256u) { ck[pos] = k; ci[pos] = (unsigned)gid; }
    } else if (k == ks) {
        unsigned pos = atomicAdd(&cnts[1], 1u);
        if (pos < 8192u) ti[pos] = (unsigned)gid;
    }
}
__global__ void k_topk_final(const unsigned* __restrict__ state, const unsigned* __restrict__ cnts,
        const unsigned* __restrict__ ck, const unsigned* __restrict__ ci,
        const unsigned* __restrict__ ti, int* __restrict__ top_pos, int* __restrict__ top_cls) {
    __shared__ unsigned kk[200], ii[200];
    int t = threadIdx.x;
    unsigned cgt = cnts[0];
    unsigned need = state[1];
    unsigned keystar = state[2];
    unsigned cntEq = cnts[1]; if (cntEq > 8192u) cntEq = 8192u;
    if ((unsigned)t < cgt && t < 200) { kk[t] = ck[t]; ii[t] = ci[t]; }
    for (unsigned e = t; e < cntEq; e += 256) {
        unsigned my = ti[e]; unsigned r = 0;
        for (unsigned j = 0; j < cntEq; j++) r += (ti[j] < my);
        if (r < need) { kk[cgt + r] = keystar; ii[cgt + r] = my; }
    }
    __syncthreads();
    if (t < 200) {
        unsigned mk = kk[t], mi = ii[t]; int r = 0;
        for (int j = 0; j < 200; j++) {
            unsigned ok = kk[j], oi = ii[j];
            r += (ok > mk) || (ok == mk && oi < mi);
        }
        top_cls[r] = (int)(mi >> 14);
        top_pos[r] = (int)(mi & 16383u);
    }
}

// ---------------- gather + class encoding + q_in ----------------
__global__ void k_gather(const float* __restrict__ lidar, const int* __restrict__ top_pos,
        const int* __restrict__ top_cls, const float* __restrict__ w_ce,
        const float* __restrict__ b_ce, const float* __restrict__ w_qpos,
        float* __restrict__ qf, float* __restrict__ qin, float* __restrict__ qpos) {
    int gid = blockIdx.x * 256 + threadIdx.x;   // 200*128
    if (gid >= 200 * 128) return;
    int p = gid >> 7, d = gid & 127;
    int idx = top_pos[p], cls = top_cls[p];
    float px = (float)(idx & 127) + 0.5f, py = (float)(idx >> 7) + 0.5f;
    float v = lidar[d * HWSZ + idx] + w_ce[d * 10 + cls] + b_ce[d];
    qf[gid] = v;
    qin[gid] = v + px * w_qpos[d * 2] + py * w_qpos[d * 2 + 1];
    if (d < 2) qpos[p * 2 + d] = (d == 0) ? px : py;
}

// ---------------- kv_in = lidar^T + bev_pos @ w_kpos^T ----------------
__global__ __launch_bounds__(256) void k_kvin(const float* __restrict__ lidar,
        const float* __restrict__ w_kpos, float* __restrict__ kv) {
    __shared__ float T[128 * 65];
    int hw0 = blockIdx.x << 6;
    int t = threadIdx.x;
    for (int i = t; i < 128 * 64; i += 256) {
        int d = i >> 6, c = i & 63;
        T[d * 65 + c] = lidar[d * HWSZ + hw0 + c];
    }
    __syncthreads();
    for (int i = t; i < 64 * 128; i += 256) {
        int r = i >> 7, d = i & 127;
        int hw = hw0 + r;
        float bx = (float)(hw & 127) + 0.5f, by = (float)(hw >> 7) + 0.5f;
        kv[hw * 128 + d] = T[d * 65 + r] + bx * w_kpos[d * 2] + by * w_kpos[d * 2 + 1];
    }
}

// ---------------- tiled fp32 GEMM  C[M,N] = A[M,K] * B[N,K]^T ----------------
// EPI: 0 plain | 2 bias+relu | 3 bias+residual | 4 head-permuted KV write
template<int EPI>
__global__ __launch_bounds__(256) void k_gemm(const float* __restrict__ A,
        const float* __restrict__ B, float* __restrict__ C, int M, int N, int K,
        const float* __restrict__ bias, const float* __restrict__ res) {
    __shared__ float As[16 * 68];
    __shared__ float Bs[16 * 68];
    int m0 = blockIdx.x * 64, n0 = blockIdx.y * 64;
    int t = threadIdx.x;
    int mi = (t & 15) << 2, ni = (t >> 4) << 2;
    float acc[4][4];
    #pragma unroll
    for (int i = 0; i < 4; i++)
        #pragma unroll
        for (int j = 0; j < 4; j++) acc[i][j] = 0.f;
    int r = t >> 2, kq = (t & 3) << 2;
    for (int k0 = 0; k0 < K; k0 += 16) {
        float4 v = make_float4(0.f, 0.f, 0.f, 0.f);
        if (m0 + r < M) v = *(const float4*)&A[(m0 + r) * K + k0 + kq];
        As[(kq + 0) * 68 + r] = v.x; As[(kq + 1) * 68 + r] = v.y;
        As[(kq + 2) * 68 + r] = v.z; As[(kq + 3) * 68 + r] = v.w;
        float4 w = *(const float4*)&B[(n0 + r) * K + k0 + kq];
        Bs[(kq + 0) * 68 + r] = w.x; Bs[(kq + 1) * 68 + r] = w.y;
        Bs[(kq + 2) * 68 + r] = w.z; Bs[(kq + 3) * 68 + r] = w.w;
        __syncthreads();
        #pragma unroll
        for (int k = 0; k < 16; k++) {
            float4 a = *(const float4*)&As[k * 68 + mi];
            float4 b = *(const float4*)&Bs[k * 68 + ni];
            acc[0][0] += a.x * b.x; acc[0][1] += a.x * b.y; acc[0][2] += a.x * b.z; acc[0][3] += a.x * b.w;
            acc[1][0] += a.y * b.x; acc[1][1] += a.y * b.y; acc[1][2] += a.y * b.z; acc[1][3] += a.y * b.w;
            acc[2][0] += a.z * b.x; acc[2][1] += a.z * b.y; acc[2][2] += a.z * b.z; acc[2][3] += a.z * b.w;
            acc[3][0] += a.w * b.x; acc[3][1] += a.w * b.y; acc[3][2] += a.w * b.z; acc[3][3] += a.w * b.w;
        }
        __syncthreads();
    }
    #pragma unroll
    for (int i = 0; i < 4; i++) {
        int m = m0 + mi + i;
        if (m >= M) continue;
        #pragma unroll
        for (int j = 0; j < 4; j++) {
            int n = n0 + ni + j;
            float v = acc[i][j];
            if (EPI == 2) v = fmaxf(v + bias[n], 0.f);
            if (EPI == 3) v += bias[n] + res[m * N + n];
            if (EPI == 4) C[((n >> 4) * HWSZ + m) * 16 + (n & 15)] = v;
            else C[m * N + n] = v;
        }
    }
}

// ---------------- split-K flash attention, 4-query register blocking ----------------
__global__ __launch_bounds__(256, 1) void k_attn_part(const float* __restrict__ Q,
        const float* __restrict__ Kp, const float* __restrict__ Vp,
        float* __restrict__ ps, float* __restrict__ pacc) {
    int head = blockIdx.y, chunk = blockIdx.z;
    int t = threadIdx.x;
    int wv = t >> 6, lane = t & 63;
    int qbase = (blockIdx.x * 4 + wv) * 4;
    float q[4][16];
    #pragma unroll
    for (int qq = 0; qq < 4; qq++) {
        int p = qbase + qq; if (p > 199) p = 199;
        const float4* qr = (const float4*)(Q + p * 128 + head * 16);
        #pragma unroll
        for (int u = 0; u < 4; u++) {
            float4 v = qr[u];
            q[qq][u * 4 + 0] = v.x * 0.25f; q[qq][u * 4 + 1] = v.y * 0.25f;
            q[qq][u * 4 + 2] = v.z * 0.25f; q[qq][u * 4 + 3] = v.w * 0.25f;
        }
    }
    const float* Kh = Kp + (size_t)head * HWSZ * 16;
    const float* Vh = Vp + (size_t)head * HWSZ * 16;
    float s[4] = {0.f, 0.f, 0.f, 0.f};
    float acc[4][16];
    #pragma unroll
    for (int qq = 0; qq < 4; qq++)
        #pragma unroll
        for (int i = 0; i < 16; i++) acc[qq][i] = 0.f;
    int k0 = chunk << 10;
    for (int kb = k0 + lane; kb < k0 + 1024; kb += 64) {
        const float4* kr = (const float4*)(Kh + (size_t)kb * 16);
        float4 ka = kr[0], kb4 = kr[1], kc = kr[2], kd = kr[3];
        float kk[16] = {ka.x, ka.y, ka.z, ka.w, kb4.x, kb4.y, kb4.z, kb4.w,
                        kc.x, kc.y, kc.z, kc.w, kd.x, kd.y, kd.z, kd.w};
        const float4* vr = (const float4*)(Vh + (size_t)kb * 16);
        float4 va = vr[0], vb = vr[1], vc = vr[2], vd = vr[3];
        float vv[16] = {va.x, va.y, va.z, va.w, vb.x, vb.y, vb.z, vb.w,
                        vc.x, vc.y, vc.z, vc.w, vd.x, vd.y, vd.z, vd.w};
        #pragma unroll
        for (int qq = 0; qq < 4; qq++) {
            float l0 = fmaf(q[qq][3], kk[3], fmaf(q[qq][2], kk[2], fmaf(q[qq][1], kk[1], q[qq][0] * kk[0])));
            float l1 = fmaf(q[qq][7], kk[7], fmaf(q[qq][6], kk[6], fmaf(q[qq][5], kk[5], q[qq][4] * kk[4])));
            float l2 = fmaf(q[qq][11], kk[11], fmaf(q[qq][10], kk[10], fmaf(q[qq][9], kk[9], q[qq][8] * kk[8])));
            float l3 = fmaf(q[qq][15], kk[15], fmaf(q[qq][14], kk[14], fmaf(q[qq][13], kk[13], q[qq][12] * kk[12])));
            float e = __expf((l0 + l1) + (l2 + l3));
            s[qq] += e;
            #pragma unroll
            for (int i = 0; i < 16; i++) acc[qq][i] = fmaf(e, vv[i], acc[qq][i]);
        }
    }
    #pragma unroll
    for (int mask = 32; mask >= 1; mask >>= 1) {
        #pragma unroll
        for (int qq = 0; qq < 4; qq++) {
            s[qq] += __shfl_xor(s[qq], mask);
            #pragma unroll
            for (int i = 0; i < 16; i++) acc[qq][i] += __shfl_xor(acc[qq][i], mask);
        }
    }
    if (lane == 0) {
        #pragma unroll
        for (int qq = 0; qq < 4; qq++) {
            int p = qbase + qq;
            int idx = (chunk * 8 + head) * 208 + p;
            ps[idx] = s[qq];
            #pragma unroll
            for (int i = 0; i < 16; i++) pacc[idx * 16 + i] = acc[qq][i];
        }
    }
}
// combine: grid (200), 128 threads = 8 heads x 16 dims
__global__ __launch_bounds__(128) void k_attn_comb(const float* __restrict__ ps,
        const float* __restrict__ pacc, float* __restrict__ out) {
    int p = blockIdx.x;
    int t = threadIdx.x;
    int h = t >> 4, d = t & 15;
    float S = 0.f, A = 0.f;
    #pragma unroll
    for (int c = 0; c < 16; c++) {
        int idx = (c * 8 + h) * 208 + p;
        S += ps[idx];
        A += pacc[idx * 16 + d];
    }
    out[p * 128 + h * 16 + d] = A / S;
}

// ---------------- LayerNorm over rows of 128 (a + optional b) ----------------
__global__ void k_ln(const float* __restrict__ a, const float* __restrict__ b,
        const float* __restrict__ g, const float* __restrict__ be, float* __restrict__ out) {
    int p = blockIdx.x, d = threadIdx.x;
    float x = a[p * 128 + d];
    if (b) x += b[p * 128 + d];
    __shared__ float red[4];
    float s = x;
    #pragma unroll
    for (int mask = 32; mask >= 1; mask >>= 1) s += __shfl_xor(s, mask);
    if ((d & 63) == 0) red[d >> 6] = s;
    __syncthreads();
    float mean = (red[0] + red[1]) * (1.f / 128.f);
    float dx = x - mean;
    float s2 = dx * dx;
    #pragma unroll
    for (int mask = 32; mask >= 1; mask >>= 1) s2 += __shfl_xor(s2, mask);
    if ((d & 63) == 0) red[2 + (d >> 6)] = s2;
    __syncthreads();
    float var = (red[2] + red[3]) * (1.f / 128.f);
    out[p * 128 + d] = dx * rsqrtf(var + 1e-5f) * g[d] + be[d];
}

// ---------------- prediction heads + score epilogue ----------------
__global__ void k_heads(const float* __restrict__ h2, const float* __restrict__ hm,
        const int* __restrict__ top_pos, const int* __restrict__ top_cls,
        const float* __restrict__ qpos,
        const float* __restrict__ w_hm, const float* __restrict__ b_hm,
        const float* __restrict__ w_rot, const float* __restrict__ b_rot,
        const float* __restrict__ w_dim, const float* __restrict__ b_dim,
        const float* __restrict__ w_center, const float* __restrict__ b_center,
        const float* __restrict__ w_height, const float* __restrict__ b_height,
        const float* __restrict__ w_vel, const float* __restrict__ b_vel,
        float* __restrict__ out) {
    int gid = blockIdx.x * 256 + threadIdx.x;
    if (gid >= 4000) return;
    int o = gid / 200, p = gid - o * 200;
    const float* wr; float bias;
    if (o < 10)      { wr = w_hm + o * 128;            bias = b_hm[o]; }
    else if (o < 12) { wr = w_rot + (o - 10) * 128;    bias = b_rot[o - 10]; }
    else if (o < 15) { wr = w_dim + (o - 12) * 128;    bias = b_dim[o - 12]; }
    else if (o < 17) { wr = w_center + (o - 15) * 128; bias = b_center[o - 15]; }
    else if (o < 18) { wr = w_height;                  bias = b_height[0]; }
    else             { wr = w_vel + (o - 18) * 128;    bias = b_vel[o - 18]; }
    const float* hr = h2 + p * 128;
    float dot = 0.f;
    #pragma unroll 8
    for (int d = 0; d < 128; d++) dot = fmaf(wr[d], hr[d], dot);
    dot += bias;
    float outv; int off;
    if (o < 10) {
        float qhs = hm[o * HWSZ + top_pos[p]];
        float oh = (top_cls[p] == o) ? 1.f : 0.f;
        outv = (1.f / (1.f + expf(-dot))) * qhs * oh;
        off = o * 200 + p;
    } else if (o < 12) { outv = dot; off = 2000 + (o - 10) * 200 + p; }
    else if (o < 15)   { outv = dot; off = 2400 + (o - 12) * 200 + p; }
    else if (o < 17)   { outv = dot + qpos[p * 2 + (o - 15)]; off = 3000 + (o - 15) * 200 + p; }
    else if (o < 18)   { outv = dot; off = 3400 + p; }
    else               { outv = dot; off = 3600 + (o - 18) * 200 + p; }
    out[off] = outv;
}

// ---------------- host ----------------
extern "C" void kernel_launch(void* const* d_in, const int* in_sizes, int n_in,
                              void* d_out, int out_size, void* d_ws, size_t ws_size,
                              hipStream_t stream) {
    const float* x        = (const float*)d_in[0];
    const float* w_shared = (const float*)d_in[1];
    const float* b_shared = (const float*)d_in[2];
    const float* w_heat   = (const float*)d_in[3];
    const float* b_heat   = (const float*)d_in[4];
    const float* w_ce     = (const float*)d_in[7];
    const float* b_ce     = (const float*)d_in[8];
    const float* w_qpos   = (const float*)d_in[9];
    const float* w_kpos   = (const float*)d_in[10];
    const float* wq       = (const float*)d_in[11];
    const float* wk       = (const float*)d_in[12];
    const float* wv       = (const float*)d_in[13];
    const float* wo       = (const float*)d_in[14];
    const float* ln1_g    = (const float*)d_in[15];
    const float* ln1_b    = (const float*)d_in[16];
    const float* ln2_g    = (const float*)d_in[17];
    const float* ln2_b    = (const float*)d_in[18];
    const float* w_ff1    = (const float*)d_in[19];
    const float* b_ff1    = (const float*)d_in[20];
    const float* w_ff2    = (const float*)d_in[21];
    const float* b_ff2    = (const float*)d_in[22];
    const float* w_center = (const float*)d_in[23];
    const float* b_center = (const float*)d_in[24];
    const float* w_height = (const float*)d_in[25];
    const float* b_height = (const float*)d_in[26];
    const float* w_dim    = (const float*)d_in[27];
    const float* b_dim    = (const float*)d_in[28];
    const float* w_rot    = (const float*)d_in[29];
    const float* b_rot    = (const float*)d_in[30];
    const float* w_vel    = (const float*)d_in[31];
    const float* b_vel    = (const float*)d_in[32];
    const float* w_hm     = (const float*)d_in[33];
    const float* b_hm     = (const float*)d_in[34];
    float* out = (float*)d_out;

    float* ws = (float*)d_ws;
    float* lidar = ws;                          // 2097152 f
    float* bigR  = lidar + 2097152;             // 8388608 f : xt_hi/xt_lo, later kvin/KpB/VpB
    ushort* xt_hi = (ushort*)bigR;              // 8388608 ushort
    ushort* xt_lo = xt_hi + 8388608;            // 8388608 ushort
    float* kvin  = bigR;                        // overlay after conv1
    float* KpB   = bigR + 2097152;
    float* VpB   = bigR + 4194304;
    float* wbh_f = bigR + 8388608;              // 294912 f
    float* wbl_f = wbh_f + 294912;              // 294912 f
    ushort* wb_hi = (ushort*)wbh_f;
    ushort* wb_lo = (ushort*)wbl_f;
    float* wt2   = wbl_f + 294912;              // 18432
    float* sig   = wt2 + 18432;                 // 163840
    float* hmb   = sig + 163840;                // 163840
    unsigned* hist_hi = (unsigned*)(hmb + 163840);   // 65536
    unsigned* hist_lo = hist_hi + 65536;        // 65536
    unsigned* state   = hist_lo + 65536;        // 64
    unsigned* cnts    = state + 64;             // 64
    unsigned* ck      = cnts + 64;              // 256
    unsigned* ci      = ck + 256;               // 256
    unsigned* ti      = ci + 256;               // 8192
    int* top_pos      = (int*)(ti + 8192);      // 256
    int* top_cls      = top_pos + 256;          // 256
    float* qpos  = (float*)(top_cls + 256);     // 512
    float* qf    = qpos + 512;                  // 25600
    float* qin   = qf + 25600;                  // 25600
    float* qbuf  = qin + 25600;                 // 25600
    float* attno = qbuf + 25600;                // 25600
    float* wo_o  = attno + 25600;               // 25600
    float* h1    = wo_o + 25600;                // 25600
    float* f1    = h1 + 25600;                  // 51200
    float* ff2o  = f1 + 51200;                  // 25600
    float* h2    = ff2o + 25600;                // 25600
    float* ps_b  = h2 + 25600;                  // 26624 (16*8*208)
    float* pacc_b = ps_b + 26624;               // 425984 (16*8*208*16)
    float* part  = pacc_b + 425984;             // 4194304 (2 x 16384 x 128)
    size_t needed = (size_t)((part + 4194304) - ws) * sizeof(float);
    if (ws_size < needed) return;

    k_prep_w2<<<72, 256, 0, stream>>>(w_heat, wt2);
    k_cvt_w<<<2304, 256, 0, stream>>>(w_shared, wb_hi, wb_lo);
    k_cvt_x<<<dim3(256, 8), 256, 0, stream>>>(x, xt_hi, xt_lo);
    k_conv1_mfma<<<256, 256, 0, stream>>>(xt_hi, xt_lo, wb_hi, wb_lo, part);
    k_conv1_fin<<<256, 256, 0, stream>>>(part, b_shared, lidar);
    k_conv2<<<256, 256, 0, stream>>>(lidar, wt2, b_heat, sig);
    k_nms<<<640, 256, 0, stream>>>(sig, hmb);
    hipMemsetAsync(hist_hi, 0, (65536u * 2 + 128) * sizeof(unsigned), stream);
    k_hist_hi<<<640, 256, 0, stream>>>(hmb, hist_hi);
    k_scan_hi<<<1, 256, 0, stream>>>(hist_hi, state);
    k_hist_lo<<<640, 256, 0, stream>>>(hmb, state, hist_lo);
    k_scan_lo<<<1, 256, 0, stream>>>(hist_lo, state);
    k_collect<<<640, 256, 0, stream>>>(hmb, state, ck, ci, ti, cnts);
    k_topk_final<<<1, 256, 0, stream>>>(state, cnts, ck, ci, ti, top_pos, top_cls);
    k_gather<<<100, 256, 0, stream>>>(lidar, top_pos, top_cls, w_ce, b_ce, w_qpos, qf, qin, qpos);
    k_kvin<<<256, 256, 0, stream>>>(lidar, w_kpos, kvin);
    k_gemm<0><<<dim3(4, 2), 256, 0, stream>>>(qin, wq, qbuf, 200, 128, 128, nullptr, nullptr);
    k_gemm<4><<<dim3(256, 2), 256, 0, stream>>>(kvin, wk, KpB, 16384, 128, 128, nullptr, nullptr);
    k_gemm<4><<<dim3(256, 2), 256, 0, stream>>>(kvin, wv, VpB, 16384, 128, 128, nullptr, nullptr);
    k_attn_part<<<dim3(13, 8, 16), 256, 0, stream>>>(qbuf, KpB, VpB, ps_b, pacc_b);
    k_attn_comb<<<200, 128, 0, stream>>>(ps_b, pacc_b, attno);
    k_gemm<0><<<dim3(4, 2), 256, 0, stream>>>(attno, wo, wo_o, 200, 128, 128, nullptr, nullptr);
    k_ln<<<200, 128, 0, stream>>>(qf, wo_o, ln1_g, ln1_b, h1);
    k_gemm<2><<<dim3(4, 4), 256, 0, stream>>>(h1, w_ff1, f1, 200, 256, 128, b_ff1, nullptr);
    k_gemm<3><<<dim3(4, 2), 256, 0, stream>>>(f1, w_ff2, ff2o, 200, 128, 256, b_ff2, h1);
    k_ln<<<200, 128, 0, stream>>>(ff2o, nullptr, ln2_g, ln2_b, h2);
    k_heads<<<16, 256, 0, stream>>>(h2, hmb, top_pos, top_cls, qpos,
        w_hm, b_hm, w_rot, b_rot, w_dim, b_dim, w_center, b_center,
        w_height, b_height, w_vel, b_vel, out);
}

// Round 7
// 528.137 us; speedup vs baseline: 1.2611x; 1.2611x over previous
//
#include <hip/hip_runtime.h>
#include <math.h>

#define HWSZ 16384

typedef __attribute__((ext_vector_type(8))) short short8;
typedef __attribute__((ext_vector_type(8))) unsigned short ush8;
typedef __attribute__((ext_vector_type(4))) float f4;
typedef __attribute__((ext_vector_type(16))) float f16x;

__device__ __forceinline__ ushort f2bf(float f) {
    unsigned u = __float_as_uint(f);
    return (ushort)((u + 0x7fffu + ((u >> 16) & 1u)) >> 16);
}
__device__ __forceinline__ float bf2f(ushort b) {
    return __uint_as_float(((unsigned)b) << 16);
}

// ---------------- weight prep ----------------
__global__ void k_prep_w2(const float* __restrict__ w, float* __restrict__ wt) {
    int idx = blockIdx.x * 256 + threadIdx.x;        // 1152*16
    if (idx >= 1152 * 16) return;
    int k = idx >> 4, oc = idx & 15;
    wt[idx] = (oc < 10) ? w[oc * 1152 + k] : 0.f;
}
// w_shared [oc][c][kh][kw] -> [oc][tap][c] bf16 hi/lo
__global__ void k_cvt_w(const float* __restrict__ w, ushort* __restrict__ wh,
                        ushort* __restrict__ wl) {
    int idx = blockIdx.x * 256 + threadIdx.x;   // 589824
    if (idx >= 589824) return;
    int oc = idx / 4608, r = idx - oc * 4608;
    int tap = r >> 9, c = r & 511;
    float f = w[oc * 4608 + c * 9 + tap];
    ushort hb = f2bf(f);
    wh[idx] = hb;
    wl[idx] = f2bf(f - bf2f(hb));
}
// wk, wv [128][128] fp32 -> bf16
__global__ void k_cvt_w128(const float* __restrict__ a, const float* __restrict__ b,
                           ushort* __restrict__ oa, ushort* __restrict__ ob) {
    int i = blockIdx.x * 256 + threadIdx.x;     // 16384
    if (i < 16384) { oa[i] = f2bf(a[i]); ob[i] = f2bf(b[i]); }
}
// x [c][hw] fp32 -> xt_hi/xt_lo [hw][c] bf16
__global__ __launch_bounds__(256) void k_cvt_x(const float* __restrict__ x,
        ushort* __restrict__ xh, ushort* __restrict__ xl) {
    __shared__ float T[64 * 65];
    int hw0 = blockIdx.x << 6;
    int c0 = blockIdx.y << 6;
    int t = threadIdx.x;
    {
        int cl = t >> 2, q = t & 3;
        const float* src = x + (size_t)(c0 + cl) * HWSZ + hw0 + q * 16;
        #pragma unroll
        for (int k = 0; k < 4; k++) {
            float4 v = *reinterpret_cast<const float4*>(src + k * 4);
            float* dst = &T[cl * 65 + q * 16 + k * 4];
            dst[0] = v.x; dst[1] = v.y; dst[2] = v.z; dst[3] = v.w;
        }
    }
    __syncthreads();
    {
        int hwl = t >> 2, q = t & 3;
        int cc = q * 16;
        size_t ob = (size_t)(hw0 + hwl) * 512 + c0 + cc;
        #pragma unroll
        for (int half = 0; half < 2; half++) {
            ush8 hv, lv;
            #pragma unroll
            for (int k = 0; k < 8; k++) {
                float f = T[(cc + half * 8 + k) * 65 + hwl];
                ushort hb = f2bf(f);
                hv[k] = hb;
                lv[k] = f2bf(f - bf2f(hb));
            }
            *reinterpret_cast<ush8*>(xh + ob + half * 8) = hv;
            *reinterpret_cast<ush8*>(xl + ob + half * 8) = lv;
        }
    }
}

// ---------------- conv1 via MFMA bf16 3-term split (R5 version) ----------------
__global__ __launch_bounds__(256) void k_conv1_mfma(
        const ushort* __restrict__ xh, const ushort* __restrict__ xl,
        const ushort* __restrict__ wh, const ushort* __restrict__ wl,
        const float* __restrict__ bias, float* __restrict__ out) {
    __shared__ ushort smem[30720];   // 61440 B
    const int t = threadIdx.x;
    const int h = blockIdx.x >> 1, w0 = (blockIdx.x & 1) << 6;
    const int l = t & 63;
    const int wid = t >> 6;
    const int wm = wid >> 1, wn = wid & 1;
    const int l15 = l & 15, lhi = l >> 4;
    const int arow = t >> 2, achk = t & 3;

    f4 acc[2][4];
    #pragma unroll
    for (int m = 0; m < 2; m++)
        #pragma unroll
        for (int n = 0; n < 4; n++) acc[m][n] = (f4){0.f, 0.f, 0.f, 0.f};

    short8 rA[2], rB[2][2];
    const short8 zz = {0, 0, 0, 0, 0, 0, 0, 0};

    auto issue = [&](int it) {
        int c0 = (it / 9) << 5;
        int tap = it % 9;
        int dh = tap / 3 - 1, dw = tap % 3 - 1;
        int hh = h + dh;
        int wg = w0 + arow + dw;
        if (hh >= 0 && hh < 128 && wg >= 0 && wg < 128) {
            size_t off = ((size_t)(hh * 128 + wg) << 9) + c0 + (achk << 3);
            rA[0] = *reinterpret_cast<const short8*>(xh + off);
            rA[1] = *reinterpret_cast<const short8*>(xl + off);
        } else { rA[0] = zz; rA[1] = zz; }
        #pragma unroll
        for (int u = 0; u < 2; u++) {
            int oc = (u << 6) + (t >> 2);
            size_t off = (size_t)oc * 4608 + tap * 512 + c0 + (achk << 3);
            rB[u][0] = *reinterpret_cast<const short8*>(wh + off);
            rB[u][1] = *reinterpret_cast<const short8*>(wl + off);
        }
    };
    auto wstage = [&](int buf) {
        *reinterpret_cast<short8*>(&smem[buf * 5120 + arow * 40 + achk * 8]) = rA[0];
        *reinterpret_cast<short8*>(&smem[buf * 5120 + 2560 + arow * 40 + achk * 8]) = rA[1];
        #pragma unroll
        for (int u = 0; u < 2; u++) {
            int oc = (u << 6) + (t >> 2);
            *reinterpret_cast<short8*>(&smem[10240 + buf * 10240 + oc * 40 + achk * 8]) = rB[u][0];
            *reinterpret_cast<short8*>(&smem[10240 + buf * 10240 + 5120 + oc * 40 + achk * 8]) = rB[u][1];
        }
    };

    issue(0);
    wstage(0);
    issue(1);
    __syncthreads();

    for (int it = 0; it < 144; ++it) {
        int buf = it & 1;
        short8 aH[2], aL[2], bH[4], bL[4];
        #pragma unroll
        for (int m = 0; m < 2; m++) {
            int row = wm * 32 + m * 16 + l15;
            aH[m] = *reinterpret_cast<const short8*>(&smem[buf * 5120 + row * 40 + lhi * 8]);
            aL[m] = *reinterpret_cast<const short8*>(&smem[buf * 5120 + 2560 + row * 40 + lhi * 8]);
        }
        #pragma unroll
        for (int n = 0; n < 4; n++) {
            int oc = wn * 64 + n * 16 + l15;
            bH[n] = *reinterpret_cast<const short8*>(&smem[10240 + buf * 10240 + oc * 40 + lhi * 8]);
            bL[n] = *reinterpret_cast<const short8*>(&smem[10240 + buf * 10240 + 5120 + oc * 40 + lhi * 8]);
        }
        #pragma unroll
        for (int m = 0; m < 2; m++)
            #pragma unroll
            for (int n = 0; n < 4; n++) {
                acc[m][n] = __builtin_amdgcn_mfma_f32_16x16x32_bf16(aH[m], bH[n], acc[m][n], 0, 0, 0);
                acc[m][n] = __builtin_amdgcn_mfma_f32_16x16x32_bf16(aL[m], bH[n], acc[m][n], 0, 0, 0);
                acc[m][n] = __builtin_amdgcn_mfma_f32_16x16x32_bf16(aH[m], bL[n], acc[m][n], 0, 0, 0);
            }
        if (it + 1 < 144) {
            wstage(buf ^ 1);
            if (it + 2 < 144) issue(it + 2);
        }
        __syncthreads();
    }

    // epilogue: bias+relu, transpose through LDS, coalesced [oc][hw] store
    float* ot = reinterpret_cast<float*>(smem);   // [64][132]
    #pragma unroll
    for (int m = 0; m < 2; m++)
        #pragma unroll
        for (int n = 0; n < 4; n++) {
            int oc = wn * 64 + n * 16 + l15;
            float b = bias[oc];
            #pragma unroll
            for (int r = 0; r < 4; r++) {
                int px = wm * 32 + m * 16 + lhi * 4 + r;
                ot[px * 132 + oc] = fmaxf(acc[m][n][r] + b, 0.f);
            }
        }
    __syncthreads();
    {
        int oc = t >> 1, half = t & 1;
        int base = h * 128 + w0 + half * 32;
        #pragma unroll
        for (int i = 0; i < 32; i += 4) {
            float4 v;
            v.x = ot[(half * 32 + i + 0) * 132 + oc];
            v.y = ot[(half * 32 + i + 1) * 132 + oc];
            v.z = ot[(half * 32 + i + 2) * 132 + oc];
            v.w = ot[(half * 32 + i + 3) * 132 + oc];
            *reinterpret_cast<float4*>(&out[(size_t)oc * HWSZ + base + i]) = v;
        }
    }
}

// ---------------- conv2: 128->10(pad16) 3x3 + bias + sigmoid ----------------
__global__ __launch_bounds__(256) void k_conv2(const float* __restrict__ lidar,
        const float* __restrict__ wt, const float* __restrict__ bias,
        float* __restrict__ sig) {
    __shared__ float xs[16 * 3 * 68];
    __shared__ float wsm[144 * 16];
    int bid = blockIdx.x;
    int h = bid >> 1, w0 = (bid & 1) << 6;
    int t = threadIdx.x;
    int tpx = (t & 15) << 2;
    int oc = t >> 4;                // 0..15 (10 real)
    float acc[4] = {0.f, 0.f, 0.f, 0.f};
    for (int c0 = 0; c0 < 128; c0 += 16) {
        for (int i = t; i < 16 * 3 * 66; i += 256) {
            int c = i / 198; int rem = i - c * 198; int r = rem / 66; int j = rem - r * 66;
            int gr = h - 1 + r, gc = w0 - 1 + j;
            float v = 0.f;
            if (((unsigned)gr < 128u) & ((unsigned)gc < 128u))
                v = lidar[(c0 + c) * HWSZ + gr * 128 + gc];
            xs[(c * 3 + r) * 68 + j] = v;
        }
        {
            const float4* src = (const float4*)(wt + c0 * 9 * 16);
            float4* dst = (float4*)wsm;
            for (int i = t; i < 576; i += 256) dst[i] = src[i];
        }
        __syncthreads();
        #pragma unroll 4
        for (int c = 0; c < 16; c++) {
            #pragma unroll
            for (int kh = 0; kh < 3; kh++) {
                const float* xr = &xs[(c * 3 + kh) * 68 + tpx];
                float xv0 = xr[0], xv1 = xr[1], xv2 = xr[2], xv3 = xr[3], xv4 = xr[4], xv5 = xr[5];
                #pragma unroll
                for (int kw = 0; kw < 3; kw++) {
                    float wv = wsm[(c * 9 + kh * 3 + kw) * 16 + oc];
                    float p0 = (kw == 0) ? xv0 : ((kw == 1) ? xv1 : xv2);
                    float p1 = (kw == 0) ? xv1 : ((kw == 1) ? xv2 : xv3);
                    float p2 = (kw == 0) ? xv2 : ((kw == 1) ? xv3 : xv4);
                    float p3 = (kw == 0) ? xv3 : ((kw == 1) ? xv4 : xv5);
                    acc[0] += p0 * wv; acc[1] += p1 * wv; acc[2] += p2 * wv; acc[3] += p3 * wv;
                }
            }
        }
        __syncthreads();
    }
    if (oc < 10) {
        float b = bias[oc];
        int col = h * 128 + w0 + tpx;
        float4 v;
        v.x = 1.f / (1.f + expf(-(acc[0] + b)));
        v.y = 1.f / (1.f + expf(-(acc[1] + b)));
        v.z = 1.f / (1.f + expf(-(acc[2] + b)));
        v.w = 1.f / (1.f + expf(-(acc[3] + b)));
        *(float4*)&sig[oc * HWSZ + col] = v;
    }
}

// ---------------- 3x3 local-max NMS ----------------
__global__ void k_nms(const float* __restrict__ sig, float* __restrict__ hm) {
    int gid = blockIdx.x * 256 + threadIdx.x;   // 163840
    int c = gid >> 14, i = gid & 16383;
    int h = i >> 7, w = i & 127;
    float v = sig[gid];
    float keep = 0.f;
    if (c >= 8) keep = v;
    else if (h >= 1 && h <= 126 && w >= 1 && w <= 126) {
        const float* s = sig + c * HWSZ;
        float m = v;
        #pragma unroll
        for (int dh = -1; dh <= 1; dh++)
            #pragma unroll
            for (int dw = -1; dw <= 1; dw++)
                m = fmaxf(m, s[(h + dh) * 128 + (w + dw)]);
        keep = (v == m) ? v : 0.f;
    }
    hm[gid] = keep;
}

// ---------------- exact top-200 radix select ----------------
__global__ void k_hist_hi(const float* __restrict__ hm, unsigned* __restrict__ hist) {
    int gid = blockIdx.x * 256 + threadIdx.x;
    unsigned k = __float_as_uint(hm[gid]);
    if (k) atomicAdd(&hist[k >> 16], 1u);
}
__global__ void k_scan_hi(const unsigned* __restrict__ hist, unsigned* __restrict__ state) {
    __shared__ unsigned ps[256];
    __shared__ int selc;
    __shared__ unsigned selcum;
    __shared__ unsigned cb[256];
    int t = threadIdx.x;
    unsigned s = 0;
    const unsigned* hp = hist + t * 256;
    for (int i = 0; i < 256; i++) s += hp[i];
    ps[t] = s;
    __syncthreads();
    if (t == 0) {
        unsigned cum = 0; int c = 255;
        for (; c > 0; c--) { if (cum + ps[c] >= 200u) break; cum += ps[c]; }
        selc = c; selcum = cum;
    }
    __syncthreads();
    int c = selc;
    cb[t] = hist[c * 256 + t];
    __syncthreads();
    if (t == 0) {
        unsigned cum = selcum; int b = 255;
        for (; b > 0; b--) { if (cum + cb[b] >= 200u) break; cum += cb[b]; }
        state[8] = (unsigned)(c * 256 + b);   // b*
        state[9] = 200u - cum;                // K'
        state[10] = cum;                      // count strictly above bin b*
    }
}
__global__ void k_hist_lo(const float* __restrict__ hm, const unsigned* __restrict__ state,
                          unsigned* __restrict__ hist) {
    int gid = blockIdx.x * 256 + threadIdx.x;
    unsigned k = __float_as_uint(hm[gid]);
    if (k && (k >> 16) == state[8]) atomicAdd(&hist[k & 0xFFFFu], 1u);
}
__global__ void k_scan_lo(const unsigned* __restrict__ hist, unsigned* __restrict__ state) {
    __shared__ unsigned ps[256];
    __shared__ int selc;
    __shared__ unsigned selcum;
    __shared__ unsigned cb[256];
    int t = threadIdx.x;
    unsigned target = state[9];
    unsigned s = 0;
    const unsigned* hp = hist + t * 256;
    for (int i = 0; i < 256; i++) s += hp[i];
    ps[t] = s;
    __syncthreads();
    if (t == 0) {
        unsigned cum = 0; int c = 255;
        for (; c > 0; c--) { if (cum + ps[c] >= target) break; cum += ps[c]; }
        selc = c; selcum = cum;
    }
    __syncthreads();
    int c = selc;
    cb[t] = hist[c * 256 + t];
    __syncthreads();
    if (t == 0) {
        unsigned cum = selcum; int b = 255;
        for (; b > 0; b--) { if (cum + cb[b] >= target) break; cum += cb[b]; }
        unsigned lstar = (unsigned)(c * 256 + b);
        state[2] = (state[8] << 16) | lstar;  // key*
        state[0] = state[10] + cum;           // C_gt
        state[1] = target - cum;              // need_eq ties
    }
}
__global__ void k_collect(const float* __restrict__ hm, const unsigned* __restrict__ state,
        unsigned* __restrict__ ck, unsigned* __restrict__ ci,
        unsigned* __restrict__ ti, unsigned* __restrict__ cnts) {
    int gid = blockIdx.x * 256 + threadIdx.x;
    unsigned k = __float_as_uint(hm[gid]);
    unsigned ks = state[2];
    if (k > ks) {
        unsigned pos = atomicAdd(&cnts[0], 1u);
        if (pos < 256u) { ck[pos] = k; ci[pos] = (unsigned)gid; }
    } else if (k == ks) {
        unsigned pos = atomicAdd(&cnts[1], 1u);
        if (pos < 8192u) ti[pos] = (unsigned)gid;
    }
}
__global__ void k_topk_final(const unsigned* __restrict__ state, const unsigned* __restrict__ cnts,
        const unsigned* __restrict__ ck, const unsigned* __restrict__ ci,
        const unsigned* __restrict__ ti, int* __restrict__ top_pos, int* __restrict__ top_cls) {
    __shared__ unsigned kk[200], ii[200];
    int t = threadIdx.x;
    unsigned cgt = cnts[0];
    unsigned need = state[1];
    unsigned keystar = state[2];
    unsigned cntEq = cnts[1]; if (cntEq > 8192u) cntEq = 8192u;
    if ((unsigned)t < cgt && t < 200) { kk[t] = ck[t]; ii[t] = ci[t]; }
    for (unsigned e = t; e < cntEq; e += 256) {
        unsigned my = ti[e]; unsigned r = 0;
        for (unsigned j = 0; j < cntEq; j++) r += (ti[j] < my);
        if (r < need) { kk[cgt + r] = keystar; ii[cgt + r] = my; }
    }
    __syncthreads();
    if (t < 200) {
        unsigned mk = kk[t], mi = ii[t]; int r = 0;
        for (int j = 0; j < 200; j++) {
            unsigned ok = kk[j], oi = ii[j];
            r += (ok > mk) || (ok == mk && oi < mi);
        }
        top_cls[r] = (int)(mi >> 14);
        top_pos[r] = (int)(mi & 16383u);
    }
}

// ---------------- gather + class encoding + q_in ----------------
__global__ void k_gather(const float* __restrict__ lidar, const int* __restrict__ top_pos,
        const int* __restrict__ top_cls, const float* __restrict__ w_ce,
        const float* __restrict__ b_ce, const float* __restrict__ w_qpos,
        float* __restrict__ qf, float* __restrict__ qin, float* __restrict__ qpos) {
    int gid = blockIdx.x * 256 + threadIdx.x;   // 200*128
    if (gid >= 200 * 128) return;
    int p = gid >> 7, d = gid & 127;
    int idx = top_pos[p], cls = top_cls[p];
    float px = (float)(idx & 127) + 0.5f, py = (float)(idx >> 7) + 0.5f;
    float v = lidar[d * HWSZ + idx] + w_ce[d * 10 + cls] + b_ce[d];
    qf[gid] = v;
    qin[gid] = v + px * w_qpos[d * 2] + py * w_qpos[d * 2 + 1];
    if (d < 2) qpos[p * 2 + d] = (d == 0) ? px : py;
}

// ---------------- kv_in = lidar^T + bev_pos @ w_kpos^T -> bf16 [hw][128] ----------------
__global__ __launch_bounds__(256) void k_kvin(const float* __restrict__ lidar,
        const float* __restrict__ w_kpos, ushort* __restrict__ kv) {
    __shared__ float T[128 * 65];
    int hw0 = blockIdx.x << 6;
    int t = threadIdx.x;
    for (int i = t; i < 128 * 64; i += 256) {
        int d = i >> 6, c = i & 63;
        T[d * 65 + c] = lidar[d * HWSZ + hw0 + c];
    }
    __syncthreads();
    for (int i = t; i < 64 * 128; i += 256) {
        int r = i >> 7, d = i & 127;
        int hw = hw0 + r;
        float bx = (float)(hw & 127) + 0.5f, by = (float)(hw >> 7) + 0.5f;
        kv[(size_t)hw * 128 + d] = f2bf(T[d * 65 + r] + bx * w_kpos[d * 2] + by * w_kpos[d * 2 + 1]);
    }
}

// ---------------- K/V projection: bf16 MFMA GEMM, EPI4 permuted store ----------------
// C[((oc>>4)*HWSZ + hw)*16 + (oc&15)] = A[hw][:] . B[oc][:]
__global__ __launch_bounds__(256) void k_gemm_kv(const ushort* __restrict__ A,
        const ushort* __restrict__ B, float* __restrict__ C) {
    __shared__ ushort As[64 * 136];     // 17408 B
    __shared__ ushort Bs[128 * 136];    // 34816 B
    int m0 = blockIdx.x << 6;
    int t = threadIdx.x;
    {
        int r = t >> 3, c = (t & 7) << 4;
        #pragma unroll
        for (int p = 0; p < 2; p++) {
            int row = p * 32 + r;
            const ush8* src = reinterpret_cast<const ush8*>(A + (size_t)(m0 + row) * 128 + c);
            *reinterpret_cast<ush8*>(&As[row * 136 + c]) = src[0];
            *reinterpret_cast<ush8*>(&As[row * 136 + c + 8]) = src[1];
        }
        #pragma unroll
        for (int p = 0; p < 4; p++) {
            int row = p * 32 + r;
            const ush8* src = reinterpret_cast<const ush8*>(B + (size_t)row * 128 + c);
            *reinterpret_cast<ush8*>(&Bs[row * 136 + c]) = src[0];
            *reinterpret_cast<ush8*>(&Bs[row * 136 + c + 8]) = src[1];
        }
    }
    __syncthreads();
    int l = t & 63, wid = t >> 6;
    int wm = wid >> 1, wn = wid & 1;
    int l31 = l & 31, lk = l >> 5;
    f16x acc[2];
    #pragma unroll
    for (int n = 0; n < 2; n++)
        #pragma unroll
        for (int i = 0; i < 16; i++) acc[n][i] = 0.f;
    #pragma unroll
    for (int ks = 0; ks < 8; ks++) {
        short8 aF = *reinterpret_cast<const short8*>(&As[(wm * 32 + l31) * 136 + ks * 16 + lk * 8]);
        #pragma unroll
        for (int n = 0; n < 2; n++) {
            short8 bF = *reinterpret_cast<const short8*>(&Bs[(wn * 64 + n * 32 + l31) * 136 + ks * 16 + lk * 8]);
            acc[n] = __builtin_amdgcn_mfma_f32_32x32x16_bf16(aF, bF, acc[n], 0, 0, 0);
        }
    }
    #pragma unroll
    for (int n = 0; n < 2; n++) {
        int oc = wn * 64 + n * 32 + l31;
        size_t cb = (size_t)(oc >> 4) * HWSZ * 16 + (oc & 15);
        #pragma unroll
        for (int r = 0; r < 16; r++) {
            int mrow = wm * 32 + (r & 3) + ((r >> 2) << 3) + (lk << 2);
            C[cb + (size_t)(m0 + mrow) * 16] = acc[n][r];
        }
    }
}

// ---------------- tiled fp32 GEMM  C[M,N] = A[M,K] * B[N,K]^T ----------------
// EPI: 0 plain | 2 bias+relu | 3 bias+residual
template<int EPI>
__global__ __launch_bounds__(256) void k_gemm(const float* __restrict__ A,
        const float* __restrict__ B, float* __restrict__ C, int M, int N, int K,
        const float* __restrict__ bias, const float* __restrict__ res) {
    __shared__ float As[16 * 68];
    __shared__ float Bs[16 * 68];
    int m0 = blockIdx.x * 64, n0 = blockIdx.y * 64;
    int t = threadIdx.x;
    int mi = (t & 15) << 2, ni = (t >> 4) << 2;
    float acc[4][4];
    #pragma unroll
    for (int i = 0; i < 4; i++)
        #pragma unroll
        for (int j = 0; j < 4; j++) acc[i][j] = 0.f;
    int r = t >> 2, kq = (t & 3) << 2;
    for (int k0 = 0; k0 < K; k0 += 16) {
        float4 v = make_float4(0.f, 0.f, 0.f, 0.f);
        if (m0 + r < M) v = *(const float4*)&A[(m0 + r) * K + k0 + kq];
        As[(kq + 0) * 68 + r] = v.x; As[(kq + 1) * 68 + r] = v.y;
        As[(kq + 2) * 68 + r] = v.z; As[(kq + 3) * 68 + r] = v.w;
        float4 w = *(const float4*)&B[(n0 + r) * K + k0 + kq];
        Bs[(kq + 0) * 68 + r] = w.x; Bs[(kq + 1) * 68 + r] = w.y;
        Bs[(kq + 2) * 68 + r] = w.z; Bs[(kq + 3) * 68 + r] = w.w;
        __syncthreads();
        #pragma unroll
        for (int k = 0; k < 16; k++) {
            float4 a = *(const float4*)&As[k * 68 + mi];
            float4 b = *(const float4*)&Bs[k * 68 + ni];
            acc[0][0] += a.x * b.x; acc[0][1] += a.x * b.y; acc[0][2] += a.x * b.z; acc[0][3] += a.x * b.w;
            acc[1][0] += a.y * b.x; acc[1][1] += a.y * b.y; acc[1][2] += a.y * b.z; acc[1][3] += a.y * b.w;
            acc[2][0] += a.z * b.x; acc[2][1] += a.z * b.y; acc[2][2] += a.z * b.z; acc[2][3] += a.z * b.w;
            acc[3][0] += a.w * b.x; acc[3][1] += a.w * b.y; acc[3][2] += a.w * b.z; acc[3][3] += a.w * b.w;
        }
        __syncthreads();
    }
    #pragma unroll
    for (int i = 0; i < 4; i++) {
        int m = m0 + mi + i;
        if (m >= M) continue;
        #pragma unroll
        for (int j = 0; j < 4; j++) {
            int n = n0 + ni + j;
            float v = acc[i][j];
            if (EPI == 2) v = fmaxf(v + bias[n], 0.f);
            if (EPI == 3) v += bias[n] + res[m * N + n];
            C[m * N + n] = v;
        }
    }
}

// ---------------- split-K flash attention, 4-query register blocking ----------------
__global__ __launch_bounds__(256, 1) void k_attn_part(const float* __restrict__ Q,
        const float* __restrict__ Kp, const float* __restrict__ Vp,
        float* __restrict__ ps, float* __restrict__ pacc) {
    int head = blockIdx.y, chunk = blockIdx.z;
    int t = threadIdx.x;
    int wv = t >> 6, lane = t & 63;
    int qbase = (blockIdx.x * 4 + wv) * 4;
    float q[4][16];
    #pragma unroll
    for (int qq = 0; qq < 4; qq++) {
        int p = qbase + qq; if (p > 199) p = 199;
        const float4* qr = (const float4*)(Q + p * 128 + head * 16);
        #pragma unroll
        for (int u = 0; u < 4; u++) {
            float4 v = qr[u];
            q[qq][u * 4 + 0] = v.x * 0.25f; q[qq][u * 4 + 1] = v.y * 0.25f;
            q[qq][u * 4 + 2] = v.z * 0.25f; q[qq][u * 4 + 3] = v.w * 0.25f;
        }
    }
    const float* Kh = Kp + (size_t)head * HWSZ * 16;
    const float* Vh = Vp + (size_t)head * HWSZ * 16;
    float s[4] = {0.f, 0.f, 0.f, 0.f};
    float acc[4][16];
    #pragma unroll
    for (int qq = 0; qq < 4; qq++)
        #pragma unroll
        for (int i = 0; i < 16; i++) acc[qq][i] = 0.f;
    int k0 = chunk << 10;
    for (int kb = k0 + lane; kb < k0 + 1024; kb += 64) {
        const float4* kr = (const float4*)(Kh + (size_t)kb * 16);
        float4 ka = kr[0], kb4 = kr[1], kc = kr[2], kd = kr[3];
        float kk[16] = {ka.x, ka.y, ka.z, ka.w, kb4.x, kb4.y, kb4.z, kb4.w,
                        kc.x, kc.y, kc.z, kc.w, kd.x, kd.y, kd.z, kd.w};
        const float4* vr = (const float4*)(Vh + (size_t)kb * 16);
        float4 va = vr[0], vb = vr[1], vc = vr[2], vd = vr[3];
        float vv[16] = {va.x, va.y, va.z, va.w, vb.x, vb.y, vb.z, vb.w,
                        vc.x, vc.y, vc.z, vc.w, vd.x, vd.y, vd.z, vd.w};
        #pragma unroll
        for (int qq = 0; qq < 4; qq++) {
            float l0 = fmaf(q[qq][3], kk[3], fmaf(q[qq][2], kk[2], fmaf(q[qq][1], kk[1], q[qq][0] * kk[0])));
            float l1 = fmaf(q[qq][7], kk[7], fmaf(q[qq][6], kk[6], fmaf(q[qq][5], kk[5], q[qq][4] * kk[4])));
            float l2 = fmaf(q[qq][11], kk[11], fmaf(q[qq][10], kk[10], fmaf(q[qq][9], kk[9], q[qq][8] * kk[8])));
            float l3 = fmaf(q[qq][15], kk[15], fmaf(q[qq][14], kk[14], fmaf(q[qq][13], kk[13], q[qq][12] * kk[12])));
            float e = __expf((l0 + l1) + (l2 + l3));
            s[qq] += e;
            #pragma unroll
            for (int i = 0; i < 16; i++) acc[qq][i] = fmaf(e, vv[i], acc[qq][i]);
        }
    }
    #pragma unroll
    for (int mask = 32; mask >= 1; mask >>= 1) {
        #pragma unroll
        for (int qq = 0; qq < 4; qq++) {
            s[qq] += __shfl_xor(s[qq], mask);
            #pragma unroll
            for (int i = 0; i < 16; i++) acc[qq][i] += __shfl_xor(acc[qq][i], mask);
        }
    }
    if (lane == 0) {
        #pragma unroll
        for (int qq = 0; qq < 4; qq++) {
            int p = qbase + qq;
            int idx = (chunk * 8 + head) * 208 + p;
            ps[idx] = s[qq];
            #pragma unroll
            for (int i = 0; i < 16; i++) pacc[idx * 16 + i] = acc[qq][i];
        }
    }
}
// combine: grid (200), 128 threads = 8 heads x 16 dims
__global__ __launch_bounds__(128) void k_attn_comb(const float* __restrict__ ps,
        const float* __restrict__ pacc, float* __restrict__ out) {
    int p = blockIdx.x;
    int t = threadIdx.x;
    int h = t >> 4, d = t & 15;
    float S = 0.f, A = 0.f;
    #pragma unroll
    for (int c = 0; c < 16; c++) {
        int idx = (c * 8 + h) * 208 + p;
        S += ps[idx];
        A += pacc[idx * 16 + d];
    }
    out[p * 128 + h * 16 + d] = A / S;
}

// ---------------- LayerNorm over rows of 128 (a + optional b) ----------------
__global__ void k_ln(const float* __restrict__ a, const float* __restrict__ b,
        const float* __restrict__ g, const float* __restrict__ be, float* __restrict__ out) {
    int p = blockIdx.x, d = threadIdx.x;
    float x = a[p * 128 + d];
    if (b) x += b[p * 128 + d];
    __shared__ float red[4];
    float s = x;
    #pragma unroll
    for (int mask = 32; mask >= 1; mask >>= 1) s += __shfl_xor(s, mask);
    if ((d & 63) == 0) red[d >> 6] = s;
    __syncthreads();
    float mean = (red[0] + red[1]) * (1.f / 128.f);
    float dx = x - mean;
    float s2 = dx * dx;
    #pragma unroll
    for (int mask = 32; mask >= 1; mask >>= 1) s2 += __shfl_xor(s2, mask);
    if ((d & 63) == 0) red[2 + (d >> 6)] = s2;
    __syncthreads();
    float var = (red[2] + red[3]) * (1.f / 128.f);
    out[p * 128 + d] = dx * rsqrtf(var + 1e-5f) * g[d] + be[d];
}

// ---------------- prediction heads + score epilogue ----------------
__global__ void k_heads(const float* __restrict__ h2, const float* __restrict__ hm,
        const int* __restrict__ top_pos, const int* __restrict__ top_cls,
        const float* __restrict__ qpos,
        const float* __restrict__ w_hm, const float* __restrict__ b_hm,
        const float* __restrict__ w_rot, const float* __restrict__ b_rot,
        const float* __restrict__ w_dim, const float* __restrict__ b_dim,
        const float* __restrict__ w_center, const float* __restrict__ b_center,
        const float* __restrict__ w_height, const float* __restrict__ b_height,
        const float* __restrict__ w_vel, const float* __restrict__ b_vel,
        float* __restrict__ out) {
    int gid = blockIdx.x * 256 + threadIdx.x;
    if (gid >= 4000) return;
    int o = gid / 200, p = gid - o * 200;
    const float* wr; float bias;
    if (o < 10)      { wr = w_hm + o * 128;            bias = b_hm[o]; }
    else if (o < 12) { wr = w_rot + (o - 10) * 128;    bias = b_rot[o - 10]; }
    else if (o < 15) { wr = w_dim + (o - 12) * 128;    bias = b_dim[o - 12]; }
    else if (o < 17) { wr = w_center + (o - 15) * 128; bias = b_center[o - 15]; }
    else if (o < 18) { wr = w_height;                  bias = b_height[0]; }
    else             { wr = w_vel + (o - 18) * 128;    bias = b_vel[o - 18]; }
    const float* hr = h2 + p * 128;
    float dot = 0.f;
    #pragma unroll 8
    for (int d = 0; d < 128; d++) dot = fmaf(wr[d], hr[d], dot);
    dot += bias;
    float outv; int off;
    if (o < 10) {
        float qhs = hm[o * HWSZ + top_pos[p]];
        float oh = (top_cls[p] == o) ? 1.f : 0.f;
        outv = (1.f / (1.f + expf(-dot))) * qhs * oh;
        off = o * 200 + p;
    } else if (o < 12) { outv = dot; off = 2000 + (o - 10) * 200 + p; }
    else if (o < 15)   { outv = dot; off = 2400 + (o - 12) * 200 + p; }
    else if (o < 17)   { outv = dot + qpos[p * 2 + (o - 15)]; off = 3000 + (o - 15) * 200 + p; }
    else if (o < 18)   { outv = dot; off = 3400 + p; }
    else               { outv = dot; off = 3600 + (o - 18) * 200 + p; }
    out[off] = outv;
}

// ---------------- host ----------------
extern "C" void kernel_launch(void* const* d_in, const int* in_sizes, int n_in,
                              void* d_out, int out_size, void* d_ws, size_t ws_size,
                              hipStream_t stream) {
    const float* x        = (const float*)d_in[0];
    const float* w_shared = (const float*)d_in[1];
    const float* b_shared = (const float*)d_in[2];
    const float* w_heat   = (const float*)d_in[3];
    const float* b_heat   = (const float*)d_in[4];
    const float* w_ce     = (const float*)d_in[7];
    const float* b_ce     = (const float*)d_in[8];
    const float* w_qpos   = (const float*)d_in[9];
    const float* w_kpos   = (const float*)d_in[10];
    const float* wq       = (const float*)d_in[11];
    const float* wk       = (const float*)d_in[12];
    const float* wv       = (const float*)d_in[13];
    const float* wo       = (const float*)d_in[14];
    const float* ln1_g    = (const float*)d_in[15];
    const float* ln1_b    = (const float*)d_in[16];
    const float* ln2_g    = (const float*)d_in[17];
    const float* ln2_b    = (const float*)d_in[18];
    const float* w_ff1    = (const float*)d_in[19];
    const float* b_ff1    = (const float*)d_in[20];
    const float* w_ff2    = (const float*)d_in[21];
    const float* b_ff2    = (const float*)d_in[22];
    const float* w_center = (const float*)d_in[23];
    const float* b_center = (const float*)d_in[24];
    const float* w_height = (const float*)d_in[25];
    const float* b_height = (const float*)d_in[26];
    const float* w_dim    = (const float*)d_in[27];
    const float* b_dim    = (const float*)d_in[28];
    const float* w_rot    = (const float*)d_in[29];
    const float* b_rot    = (const float*)d_in[30];
    const float* w_vel    = (const float*)d_in[31];
    const float* b_vel    = (const float*)d_in[32];
    const float* w_hm     = (const float*)d_in[33];
    const float* b_hm     = (const float*)d_in[34];
    float* out = (float*)d_out;

    float* ws = (float*)d_ws;
    float* lidar = ws;                          // 2097152 f
    float* bigR  = lidar + 2097152;             // 8388608 f : xt_hi/xt_lo, later kvb/KpB/VpB
    ushort* xt_hi = (ushort*)bigR;              // 8388608 ushort
    ushort* xt_lo = xt_hi + 8388608;            // 8388608 ushort
    ushort* kvb  = (ushort*)bigR;               // bf16 [hw][128], overlay after conv1
    float* KpB   = bigR + 2097152;
    float* VpB   = bigR + 4194304;
    float* wbh_f = bigR + 8388608;              // 294912 f
    float* wbl_f = wbh_f + 294912;              // 294912 f
    ushort* wb_hi = (ushort*)wbh_f;
    ushort* wb_lo = (ushort*)wbl_f;
    float* wt2   = wbl_f + 294912;              // 18432
    float* sig   = wt2 + 18432;                 // 163840
    float* hmb   = sig + 163840;                // 163840
    unsigned* hist_hi = (unsigned*)(hmb + 163840);   // 65536
    unsigned* hist_lo = hist_hi + 65536;        // 65536
    unsigned* state   = hist_lo + 65536;        // 64
    unsigned* cnts    = state + 64;             // 64
    unsigned* ck      = cnts + 64;              // 256
    unsigned* ci      = ck + 256;               // 256
    unsigned* ti      = ci + 256;               // 8192
    int* top_pos      = (int*)(ti + 8192);      // 256
    int* top_cls      = top_pos + 256;          // 256
    float* qpos  = (float*)(top_cls + 256);     // 512
    float* qf    = qpos + 512;                  // 25600
    float* qin   = qf + 25600;                  // 25600
    float* qbuf  = qin + 25600;                 // 25600
    float* attno = qbuf + 25600;                // 25600
    float* wo_o  = attno + 25600;               // 25600
    float* h1    = wo_o + 25600;                // 25600
    float* f1    = h1 + 25600;                  // 51200
    float* ff2o  = f1 + 51200;                  // 25600
    float* h2    = ff2o + 25600;                // 25600
    float* ps_b  = h2 + 25600;                  // 26624 (16*8*208)
    float* pacc_b = ps_b + 26624;               // 425984 (16*8*208*16)
    ushort* wkb  = (ushort*)(pacc_b + 425984);  // 16384 ush
    ushort* wvb  = wkb + 16384;                 // 16384 ush
    size_t needed = (size_t)((pacc_b + 425984 + 16384) - ws) * sizeof(float);
    if (ws_size < needed) return;

    k_prep_w2<<<72, 256, 0, stream>>>(w_heat, wt2);
    k_cvt_w<<<2304, 256, 0, stream>>>(w_shared, wb_hi, wb_lo);
    k_cvt_w128<<<64, 256, 0, stream>>>(wk, wv, wkb, wvb);
    k_cvt_x<<<dim3(256, 8), 256, 0, stream>>>(x, xt_hi, xt_lo);
    k_conv1_mfma<<<256, 256, 0, stream>>>(xt_hi, xt_lo, wb_hi, wb_lo, b_shared, lidar);
    k_conv2<<<256, 256, 0, stream>>>(lidar, wt2, b_heat, sig);
    k_nms<<<640, 256, 0, stream>>>(sig, hmb);
    hipMemsetAsync(hist_hi, 0, (65536u * 2 + 128) * sizeof(unsigned), stream);
    k_hist_hi<<<640, 256, 0, stream>>>(hmb, hist_hi);
    k_scan_hi<<<1, 256, 0, stream>>>(hist_hi, state);
    k_hist_lo<<<640, 256, 0, stream>>>(hmb, state, hist_lo);
    k_scan_lo<<<1, 256, 0, stream>>>(hist_lo, state);
    k_collect<<<640, 256, 0, stream>>>(hmb, state, ck, ci, ti, cnts);
    k_topk_final<<<1, 256, 0, stream>>>(state, cnts, ck, ci, ti, top_pos, top_cls);
    k_gather<<<100, 256, 0, stream>>>(lidar, top_pos, top_cls, w_ce, b_ce, w_qpos, qf, qin, qpos);
    k_kvin<<<256, 256, 0, stream>>>(lidar, w_kpos, kvb);
    k_gemm<0><<<dim3(4, 2), 256, 0, stream>>>(qin, wq, qbuf, 200, 128, 128, nullptr, nullptr);
    k_gemm_kv<<<256, 256, 0, stream>>>(kvb, wkb, KpB);
    k_gemm_kv<<<256, 256, 0, stream>>>(kvb, wvb, VpB);
    k_attn_part<<<dim3(13, 8, 16), 256, 0, stream>>>(qbuf, KpB, VpB, ps_b, pacc_b);
    k_attn_comb<<<200, 128, 0, stream>>>(ps_b, pacc_b, attno);
    k_gemm<0><<<dim3(4, 2), 256, 0, stream>>>(attno, wo, wo_o, 200, 128, 128, nullptr, nullptr);
    k_ln<<<200, 128, 0, stream>>>(qf, wo_o, ln1_g, ln1_b, h1);
    k_gemm<2><<<dim3(4, 4), 256, 0, stream>>>(h1, w_ff1, f1, 200, 256, 128, b_ff1, nullptr);
    k_gemm<3><<<dim3(4, 2), 256, 0, stream>>>(f1, w_ff2, ff2o, 200, 128, 256, b_ff2, h1);
    k_ln<<<200, 128, 0, stream>>>(ff2o, nullptr, ln2_g, ln2_b, h2);
    k_heads<<<16, 256, 0, stream>>>(h2, hmb, top_pos, top_cls, qpos,
        w_hm, b_hm, w_rot, b_rot, w_dim, b_dim, w_center, b_center,
        w_height, b_height, w_vel, b_vel, out);
}

// Round 8
// 496.748 us; speedup vs baseline: 1.3408x; 1.0632x over previous
//
#include <hip/hip_runtime.h>
#include <math.h>

#define HWSZ 16384

typedef __attribute__((ext_vector_type(8))) short short8;
typedef __attribute__((ext_vector_type(8))) unsigned short ush8;
typedef __attribute__((ext_vector_type(4))) float f4;
typedef __attribute__((ext_vector_type(16))) float f16x;

__device__ __forceinline__ ushort f2bf(float f) {
    unsigned u = __float_as_uint(f);
    return (ushort)((u + 0x7fffu + ((u >> 16) & 1u)) >> 16);
}
__device__ __forceinline__ float bf2f(ushort b) {
    return __uint_as_float(((unsigned)b) << 16);
}

// ---------------- weight prep ----------------
__global__ void k_prep_w2(const float* __restrict__ w, float* __restrict__ wt) {
    int idx = blockIdx.x * 256 + threadIdx.x;        // 1152*16
    if (idx >= 1152 * 16) return;
    int k = idx >> 4, oc = idx & 15;
    wt[idx] = (oc < 10) ? w[oc * 1152 + k] : 0.f;
}
// w_shared [oc][c][kh][kw] -> [oc][tap][c] bf16 hi/lo
__global__ void k_cvt_w(const float* __restrict__ w, ushort* __restrict__ wh,
                        ushort* __restrict__ wl) {
    int idx = blockIdx.x * 256 + threadIdx.x;   // 589824
    if (idx >= 589824) return;
    int oc = idx / 4608, r = idx - oc * 4608;
    int tap = r >> 9, c = r & 511;
    float f = w[oc * 4608 + c * 9 + tap];
    ushort hb = f2bf(f);
    wh[idx] = hb;
    wl[idx] = f2bf(f - bf2f(hb));
}
// wk, wv [128][128] fp32 -> bf16
__global__ void k_cvt_w128(const float* __restrict__ a, const float* __restrict__ b,
                           ushort* __restrict__ oa, ushort* __restrict__ ob) {
    int i = blockIdx.x * 256 + threadIdx.x;     // 16384
    if (i < 16384) { oa[i] = f2bf(a[i]); ob[i] = f2bf(b[i]); }
}
// x [c][hw] fp32 -> xt_hi/xt_lo [hw][c] bf16
__global__ __launch_bounds__(256) void k_cvt_x(const float* __restrict__ x,
        ushort* __restrict__ xh, ushort* __restrict__ xl) {
    __shared__ float T[64 * 65];
    int hw0 = blockIdx.x << 6;
    int c0 = blockIdx.y << 6;
    int t = threadIdx.x;
    {
        int cl = t >> 2, q = t & 3;
        const float* src = x + (size_t)(c0 + cl) * HWSZ + hw0 + q * 16;
        #pragma unroll
        for (int k = 0; k < 4; k++) {
            float4 v = *reinterpret_cast<const float4*>(src + k * 4);
            float* dst = &T[cl * 65 + q * 16 + k * 4];
            dst[0] = v.x; dst[1] = v.y; dst[2] = v.z; dst[3] = v.w;
        }
    }
    __syncthreads();
    {
        int hwl = t >> 2, q = t & 3;
        int cc = q * 16;
        size_t ob = (size_t)(hw0 + hwl) * 512 + c0 + cc;
        #pragma unroll
        for (int half = 0; half < 2; half++) {
            ush8 hv, lv;
            #pragma unroll
            for (int k = 0; k < 8; k++) {
                float f = T[(cc + half * 8 + k) * 65 + hwl];
                ushort hb = f2bf(f);
                hv[k] = hb;
                lv[k] = f2bf(f - bf2f(hb));
            }
            *reinterpret_cast<ush8*>(xh + ob + half * 8) = hv;
            *reinterpret_cast<ush8*>(xl + ob + half * 8) = lv;
        }
    }
}

// ---------------- conv1 via MFMA bf16 3-term split ----------------
__global__ __launch_bounds__(256) void k_conv1_mfma(
        const ushort* __restrict__ xh, const ushort* __restrict__ xl,
        const ushort* __restrict__ wh, const ushort* __restrict__ wl,
        const float* __restrict__ bias, float* __restrict__ out) {
    __shared__ ushort smem[30720];   // 61440 B
    const int t = threadIdx.x;
    const int h = blockIdx.x >> 1, w0 = (blockIdx.x & 1) << 6;
    const int l = t & 63;
    const int wid = t >> 6;
    const int wm = wid >> 1, wn = wid & 1;
    const int l15 = l & 15, lhi = l >> 4;
    const int arow = t >> 2, achk = t & 3;

    f4 acc[2][4];
    #pragma unroll
    for (int m = 0; m < 2; m++)
        #pragma unroll
        for (int n = 0; n < 4; n++) acc[m][n] = (f4){0.f, 0.f, 0.f, 0.f};

    short8 rA[2], rB[2][2];
    const short8 zz = {0, 0, 0, 0, 0, 0, 0, 0};

    auto issue = [&](int it) {
        int c0 = (it / 9) << 5;
        int tap = it % 9;
        int dh = tap / 3 - 1, dw = tap % 3 - 1;
        int hh = h + dh;
        int wg = w0 + arow + dw;
        if (hh >= 0 && hh < 128 && wg >= 0 && wg < 128) {
            size_t off = ((size_t)(hh * 128 + wg) << 9) + c0 + (achk << 3);
            rA[0] = *reinterpret_cast<const short8*>(xh + off);
            rA[1] = *reinterpret_cast<const short8*>(xl + off);
        } else { rA[0] = zz; rA[1] = zz; }
        #pragma unroll
        for (int u = 0; u < 2; u++) {
            int oc = (u << 6) + (t >> 2);
            size_t off = (size_t)oc * 4608 + tap * 512 + c0 + (achk << 3);
            rB[u][0] = *reinterpret_cast<const short8*>(wh + off);
            rB[u][1] = *reinterpret_cast<const short8*>(wl + off);
        }
    };
    auto wstage = [&](int buf) {
        *reinterpret_cast<short8*>(&smem[buf * 5120 + arow * 40 + achk * 8]) = rA[0];
        *reinterpret_cast<short8*>(&smem[buf * 5120 + 2560 + arow * 40 + achk * 8]) = rA[1];
        #pragma unroll
        for (int u = 0; u < 2; u++) {
            int oc = (u << 6) + (t >> 2);
            *reinterpret_cast<short8*>(&smem[10240 + buf * 10240 + oc * 40 + achk * 8]) = rB[u][0];
            *reinterpret_cast<short8*>(&smem[10240 + buf * 10240 + 5120 + oc * 40 + achk * 8]) = rB[u][1];
        }
    };

    issue(0);
    wstage(0);
    issue(1);
    __syncthreads();

    for (int it = 0; it < 144; ++it) {
        int buf = it & 1;
        short8 aH[2], aL[2], bH[4], bL[4];
        #pragma unroll
        for (int m = 0; m < 2; m++) {
            int row = wm * 32 + m * 16 + l15;
            aH[m] = *reinterpret_cast<const short8*>(&smem[buf * 5120 + row * 40 + lhi * 8]);
            aL[m] = *reinterpret_cast<const short8*>(&smem[buf * 5120 + 2560 + row * 40 + lhi * 8]);
        }
        #pragma unroll
        for (int n = 0; n < 4; n++) {
            int oc = wn * 64 + n * 16 + l15;
            bH[n] = *reinterpret_cast<const short8*>(&smem[10240 + buf * 10240 + oc * 40 + lhi * 8]);
            bL[n] = *reinterpret_cast<const short8*>(&smem[10240 + buf * 10240 + 5120 + oc * 40 + lhi * 8]);
        }
        #pragma unroll
        for (int m = 0; m < 2; m++)
            #pragma unroll
            for (int n = 0; n < 4; n++) {
                acc[m][n] = __builtin_amdgcn_mfma_f32_16x16x32_bf16(aH[m], bH[n], acc[m][n], 0, 0, 0);
                acc[m][n] = __builtin_amdgcn_mfma_f32_16x16x32_bf16(aL[m], bH[n], acc[m][n], 0, 0, 0);
                acc[m][n] = __builtin_amdgcn_mfma_f32_16x16x32_bf16(aH[m], bL[n], acc[m][n], 0, 0, 0);
            }
        if (it + 1 < 144) {
            wstage(buf ^ 1);
            if (it + 2 < 144) issue(it + 2);
        }
        __syncthreads();
    }

    // epilogue: bias+relu, transpose through LDS, coalesced [oc][hw] store
    float* ot = reinterpret_cast<float*>(smem);   // [64][132]
    #pragma unroll
    for (int m = 0; m < 2; m++)
        #pragma unroll
        for (int n = 0; n < 4; n++) {
            int oc = wn * 64 + n * 16 + l15;
            float b = bias[oc];
            #pragma unroll
            for (int r = 0; r < 4; r++) {
                int px = wm * 32 + m * 16 + lhi * 4 + r;
                ot[px * 132 + oc] = fmaxf(acc[m][n][r] + b, 0.f);
            }
        }
    __syncthreads();
    {
        int oc = t >> 1, half = t & 1;
        int base = h * 128 + w0 + half * 32;
        #pragma unroll
        for (int i = 0; i < 32; i += 4) {
            float4 v;
            v.x = ot[(half * 32 + i + 0) * 132 + oc];
            v.y = ot[(half * 32 + i + 1) * 132 + oc];
            v.z = ot[(half * 32 + i + 2) * 132 + oc];
            v.w = ot[(half * 32 + i + 3) * 132 + oc];
            *reinterpret_cast<float4*>(&out[(size_t)oc * HWSZ + base + i]) = v;
        }
    }
}

// ---------------- conv2: 128->10(pad16) 3x3 + bias + sigmoid ----------------
__global__ __launch_bounds__(256) void k_conv2(const float* __restrict__ lidar,
        const float* __restrict__ wt, const float* __restrict__ bias,
        float* __restrict__ sig) {
    __shared__ float xs[16 * 3 * 68];
    __shared__ float wsm[144 * 16];
    int bid = blockIdx.x;
    int h = bid >> 1, w0 = (bid & 1) << 6;
    int t = threadIdx.x;
    int tpx = (t & 15) << 2;
    int oc = t >> 4;                // 0..15 (10 real)
    float acc[4] = {0.f, 0.f, 0.f, 0.f};
    for (int c0 = 0; c0 < 128; c0 += 16) {
        for (int i = t; i < 16 * 3 * 66; i += 256) {
            int c = i / 198; int rem = i - c * 198; int r = rem / 66; int j = rem - r * 66;
            int gr = h - 1 + r, gc = w0 - 1 + j;
            float v = 0.f;
            if (((unsigned)gr < 128u) & ((unsigned)gc < 128u))
                v = lidar[(c0 + c) * HWSZ + gr * 128 + gc];
            xs[(c * 3 + r) * 68 + j] = v;
        }
        {
            const float4* src = (const float4*)(wt + c0 * 9 * 16);
            float4* dst = (float4*)wsm;
            for (int i = t; i < 576; i += 256) dst[i] = src[i];
        }
        __syncthreads();
        #pragma unroll 4
        for (int c = 0; c < 16; c++) {
            #pragma unroll
            for (int kh = 0; kh < 3; kh++) {
                const float* xr = &xs[(c * 3 + kh) * 68 + tpx];
                float xv0 = xr[0], xv1 = xr[1], xv2 = xr[2], xv3 = xr[3], xv4 = xr[4], xv5 = xr[5];
                #pragma unroll
                for (int kw = 0; kw < 3; kw++) {
                    float wv = wsm[(c * 9 + kh * 3 + kw) * 16 + oc];
                    float p0 = (kw == 0) ? xv0 : ((kw == 1) ? xv1 : xv2);
                    float p1 = (kw == 0) ? xv1 : ((kw == 1) ? xv2 : xv3);
                    float p2 = (kw == 0) ? xv2 : ((kw == 1) ? xv3 : xv4);
                    float p3 = (kw == 0) ? xv3 : ((kw == 1) ? xv4 : xv5);
                    acc[0] += p0 * wv; acc[1] += p1 * wv; acc[2] += p2 * wv; acc[3] += p3 * wv;
                }
            }
        }
        __syncthreads();
    }
    if (oc < 10) {
        float b = bias[oc];
        int col = h * 128 + w0 + tpx;
        float4 v;
        v.x = 1.f / (1.f + expf(-(acc[0] + b)));
        v.y = 1.f / (1.f + expf(-(acc[1] + b)));
        v.z = 1.f / (1.f + expf(-(acc[2] + b)));
        v.w = 1.f / (1.f + expf(-(acc[3] + b)));
        *(float4*)&sig[oc * HWSZ + col] = v;
    }
}

// ---------------- 3x3 local-max NMS + fused hi-histogram ----------------
__global__ void k_nms(const float* __restrict__ sig, float* __restrict__ hm,
                      unsigned* __restrict__ hist) {
    int gid = blockIdx.x * 256 + threadIdx.x;   // 163840
    int c = gid >> 14, i = gid & 16383;
    int h = i >> 7, w = i & 127;
    float v = sig[gid];
    float keep = 0.f;
    if (c >= 8) keep = v;
    else if (h >= 1 && h <= 126 && w >= 1 && w <= 126) {
        const float* s = sig + c * HWSZ;
        float m = v;
        #pragma unroll
        for (int dh = -1; dh <= 1; dh++)
            #pragma unroll
            for (int dw = -1; dw <= 1; dw++)
                m = fmaxf(m, s[(h + dh) * 128 + (w + dw)]);
        keep = (v == m) ? v : 0.f;
    }
    hm[gid] = keep;
    unsigned kb = __float_as_uint(keep);
    if (kb) atomicAdd(&hist[kb >> 16], 1u);
}

// ---------------- exact top-200 radix select ----------------
__global__ void k_scan_hi(const unsigned* __restrict__ hist, unsigned* __restrict__ state) {
    __shared__ unsigned ps[256];
    __shared__ int selc;
    __shared__ unsigned selcum;
    __shared__ unsigned cb[256];
    int t = threadIdx.x;
    unsigned s = 0;
    const unsigned* hp = hist + t * 256;
    for (int i = 0; i < 256; i++) s += hp[i];
    ps[t] = s;
    __syncthreads();
    if (t == 0) {
        unsigned cum = 0; int c = 255;
        for (; c > 0; c--) { if (cum + ps[c] >= 200u) break; cum += ps[c]; }
        selc = c; selcum = cum;
    }
    __syncthreads();
    int c = selc;
    cb[t] = hist[c * 256 + t];
    __syncthreads();
    if (t == 0) {
        unsigned cum = selcum; int b = 255;
        for (; b > 0; b--) { if (cum + cb[b] >= 200u) break; cum += cb[b]; }
        state[8] = (unsigned)(c * 256 + b);   // b*
        state[9] = 200u - cum;                // K'
        state[10] = cum;                      // count strictly above bin b*
    }
}
__global__ void k_hist_lo(const float* __restrict__ hm, const unsigned* __restrict__ state,
                          unsigned* __restrict__ hist) {
    int gid = blockIdx.x * 256 + threadIdx.x;
    unsigned k = __float_as_uint(hm[gid]);
    if (k && (k >> 16) == state[8]) atomicAdd(&hist[k & 0xFFFFu], 1u);
}
__global__ void k_scan_lo(const unsigned* __restrict__ hist, unsigned* __restrict__ state) {
    __shared__ unsigned ps[256];
    __shared__ int selc;
    __shared__ unsigned selcum;
    __shared__ unsigned cb[256];
    int t = threadIdx.x;
    unsigned target = state[9];
    unsigned s = 0;
    const unsigned* hp = hist + t * 256;
    for (int i = 0; i < 256; i++) s += hp[i];
    ps[t] = s;
    __syncthreads();
    if (t == 0) {
        unsigned cum = 0; int c = 255;
        for (; c > 0; c--) { if (cum + ps[c] >= target) break; cum += ps[c]; }
        selc = c; selcum = cum;
    }
    __syncthreads();
    int c = selc;
    cb[t] = hist[c * 256 + t];
    __syncthreads();
    if (t == 0) {
        unsigned cum = selcum; int b = 255;
        for (; b > 0; b--) { if (cum + cb[b] >= target) break; cum += cb[b]; }
        unsigned lstar = (unsigned)(c * 256 + b);
        state[2] = (state[8] << 16) | lstar;  // key*
        state[0] = state[10] + cum;           // C_gt
        state[1] = target - cum;              // need_eq ties
    }
}
__global__ void k_collect(const float* __restrict__ hm, const unsigned* __restrict__ state,
        unsigned* __restrict__ ck, unsigned* __restrict__ ci,
        unsigned* __restrict__ ti, unsigned* __restrict__ cnts) {
    int gid = blockIdx.x * 256 + threadIdx.x;
    unsigned k = __float_as_uint(hm[gid]);
    unsigned ks = state[2];
    if (k > ks) {
        unsigned pos = atomicAdd(&cnts[0], 1u);
        if (pos < 256u) { ck[pos] = k; ci[pos] = (unsigned)gid; }
    } else if (k == ks) {
        unsigned pos = atomicAdd(&cnts[1], 1u);
        if (pos < 8192u) ti[pos] = (unsigned)gid;
    }
}
__global__ void k_topk_final(const unsigned* __restrict__ state, const unsigned* __restrict__ cnts,
        const unsigned* __restrict__ ck, const unsigned* __restrict__ ci,
        const unsigned* __restrict__ ti, int* __restrict__ top_pos, int* __restrict__ top_cls) {
    __shared__ unsigned kk[200], ii[200];
    int t = threadIdx.x;
    unsigned cgt = cnts[0];
    unsigned need = state[1];
    unsigned keystar = state[2];
    unsigned cntEq = cnts[1]; if (cntEq > 8192u) cntEq = 8192u;
    if ((unsigned)t < cgt && t < 200) { kk[t] = ck[t]; ii[t] = ci[t]; }
    for (unsigned e = t; e < cntEq; e += 256) {
        unsigned my = ti[e]; unsigned r = 0;
        for (unsigned j = 0; j < cntEq; j++) r += (ti[j] < my);
        if (r < need) { kk[cgt + r] = keystar; ii[cgt + r] = my; }
    }
    __syncthreads();
    if (t < 200) {
        unsigned mk = kk[t], mi = ii[t]; int r = 0;
        for (int j = 0; j < 200; j++) {
            unsigned ok = kk[j], oi = ii[j];
            r += (ok > mk) || (ok == mk && oi < mi);
        }
        top_cls[r] = (int)(mi >> 14);
        top_pos[r] = (int)(mi & 16383u);
    }
}

// ---------------- gather + class encoding + q_in ----------------
__global__ void k_gather(const float* __restrict__ lidar, const int* __restrict__ top_pos,
        const int* __restrict__ top_cls, const float* __restrict__ w_ce,
        const float* __restrict__ b_ce, const float* __restrict__ w_qpos,
        float* __restrict__ qf, float* __restrict__ qin, float* __restrict__ qpos) {
    int gid = blockIdx.x * 256 + threadIdx.x;   // 200*128
    if (gid >= 200 * 128) return;
    int p = gid >> 7, d = gid & 127;
    int idx = top_pos[p], cls = top_cls[p];
    float px = (float)(idx & 127) + 0.5f, py = (float)(idx >> 7) + 0.5f;
    float v = lidar[d * HWSZ + idx] + w_ce[d * 10 + cls] + b_ce[d];
    qf[gid] = v;
    qin[gid] = v + px * w_qpos[d * 2] + py * w_qpos[d * 2 + 1];
    if (d < 2) qpos[p * 2 + d] = (d == 0) ? px : py;
}

// ---------------- kv_in = lidar^T + bev_pos @ w_kpos^T -> bf16 [hw][128] ----------------
__global__ __launch_bounds__(256) void k_kvin(const float* __restrict__ lidar,
        const float* __restrict__ w_kpos, ushort* __restrict__ kv) {
    __shared__ float T[128 * 65];
    int hw0 = blockIdx.x << 6;
    int t = threadIdx.x;
    for (int i = t; i < 128 * 64; i += 256) {
        int d = i >> 6, c = i & 63;
        T[d * 65 + c] = lidar[d * HWSZ + hw0 + c];
    }
    __syncthreads();
    for (int i = t; i < 64 * 128; i += 256) {
        int r = i >> 7, d = i & 127;
        int hw = hw0 + r;
        float bx = (float)(hw & 127) + 0.5f, by = (float)(hw >> 7) + 0.5f;
        kv[(size_t)hw * 128 + d] = f2bf(T[d * 65 + r] + bx * w_kpos[d * 2] + by * w_kpos[d * 2 + 1]);
    }
}

// ---------------- K/V projection: bf16 MFMA GEMM, bf16 permuted store ----------------
__global__ __launch_bounds__(256) void k_gemm_kv(const ushort* __restrict__ A,
        const ushort* __restrict__ B, ushort* __restrict__ C) {
    __shared__ ushort As[64 * 136];     // 17408 B
    __shared__ ushort Bs[128 * 136];    // 34816 B
    int m0 = blockIdx.x << 6;
    int t = threadIdx.x;
    {
        int r = t >> 3, c = (t & 7) << 4;
        #pragma unroll
        for (int p = 0; p < 2; p++) {
            int row = p * 32 + r;
            const ush8* src = reinterpret_cast<const ush8*>(A + (size_t)(m0 + row) * 128 + c);
            *reinterpret_cast<ush8*>(&As[row * 136 + c]) = src[0];
            *reinterpret_cast<ush8*>(&As[row * 136 + c + 8]) = src[1];
        }
        #pragma unroll
        for (int p = 0; p < 4; p++) {
            int row = p * 32 + r;
            const ush8* src = reinterpret_cast<const ush8*>(B + (size_t)row * 128 + c);
            *reinterpret_cast<ush8*>(&Bs[row * 136 + c]) = src[0];
            *reinterpret_cast<ush8*>(&Bs[row * 136 + c + 8]) = src[1];
        }
    }
    __syncthreads();
    int l = t & 63, wid = t >> 6;
    int wm = wid >> 1, wn = wid & 1;
    int l31 = l & 31, lk = l >> 5;
    f16x acc[2];
    #pragma unroll
    for (int n = 0; n < 2; n++)
        #pragma unroll
        for (int i = 0; i < 16; i++) acc[n][i] = 0.f;
    #pragma unroll
    for (int ks = 0; ks < 8; ks++) {
        short8 aF = *reinterpret_cast<const short8*>(&As[(wm * 32 + l31) * 136 + ks * 16 + lk * 8]);
        #pragma unroll
        for (int n = 0; n < 2; n++) {
            short8 bF = *reinterpret_cast<const short8*>(&Bs[(wn * 64 + n * 32 + l31) * 136 + ks * 16 + lk * 8]);
            acc[n] = __builtin_amdgcn_mfma_f32_32x32x16_bf16(aF, bF, acc[n], 0, 0, 0);
        }
    }
    #pragma unroll
    for (int n = 0; n < 2; n++) {
        int oc = wn * 64 + n * 32 + l31;
        size_t cb = (size_t)(oc >> 4) * HWSZ * 16 + (oc & 15);
        #pragma unroll
        for (int r = 0; r < 16; r++) {
            int mrow = wm * 32 + (r & 3) + ((r >> 2) << 3) + (lk << 2);
            C[cb + (size_t)(m0 + mrow) * 16] = f2bf(acc[n][r]);
        }
    }
}

// ---------------- tiled fp32 GEMM  C[M,N] = A[M,K] * B[N,K]^T (EPI 0 only used) ----------------
template<int EPI>
__global__ __launch_bounds__(256) void k_gemm(const float* __restrict__ A,
        const float* __restrict__ B, float* __restrict__ C, int M, int N, int K,
        const float* __restrict__ bias, const float* __restrict__ res) {
    __shared__ float As[16 * 68];
    __shared__ float Bs[16 * 68];
    int m0 = blockIdx.x * 64, n0 = blockIdx.y * 64;
    int t = threadIdx.x;
    int mi = (t & 15) << 2, ni = (t >> 4) << 2;
    float acc[4][4];
    #pragma unroll
    for (int i = 0; i < 4; i++)
        #pragma unroll
        for (int j = 0; j < 4; j++) acc[i][j] = 0.f;
    int r = t >> 2, kq = (t & 3) << 2;
    for (int k0 = 0; k0 < K; k0 += 16) {
        float4 v = make_float4(0.f, 0.f, 0.f, 0.f);
        if (m0 + r < M) v = *(const float4*)&A[(m0 + r) * K + k0 + kq];
        As[(kq + 0) * 68 + r] = v.x; As[(kq + 1) * 68 + r] = v.y;
        As[(kq + 2) * 68 + r] = v.z; As[(kq + 3) * 68 + r] = v.w;
        float4 w = *(const float4*)&B[(n0 + r) * K + k0 + kq];
        Bs[(kq + 0) * 68 + r] = w.x; Bs[(kq + 1) * 68 + r] = w.y;
        Bs[(kq + 2) * 68 + r] = w.z; Bs[(kq + 3) * 68 + r] = w.w;
        __syncthreads();
        #pragma unroll
        for (int k = 0; k < 16; k++) {
            float4 a = *(const float4*)&As[k * 68 + mi];
            float4 b = *(const float4*)&Bs[k * 68 + ni];
            acc[0][0] += a.x * b.x; acc[0][1] += a.x * b.y; acc[0][2] += a.x * b.z; acc[0][3] += a.x * b.w;
            acc[1][0] += a.y * b.x; acc[1][1] += a.y * b.y; acc[1][2] += a.y * b.z; acc[1][3] += a.y * b.w;
            acc[2][0] += a.z * b.x; acc[2][1] += a.z * b.y; acc[2][2] += a.z * b.z; acc[2][3] += a.z * b.w;
            acc[3][0] += a.w * b.x; acc[3][1] += a.w * b.y; acc[3][2] += a.w * b.z; acc[3][3] += a.w * b.w;
        }
        __syncthreads();
    }
    #pragma unroll
    for (int i = 0; i < 4; i++) {
        int m = m0 + mi + i;
        if (m >= M) continue;
        #pragma unroll
        for (int j = 0; j < 4; j++) {
            int n = n0 + ni + j;
            float v = acc[i][j];
            if (EPI == 2) v = fmaxf(v + bias[n], 0.f);
            if (EPI == 3) v += bias[n] + res[m * N + n];
            C[m * N + n] = v;
        }
    }
}

// ---------------- split-K flash attention, 4-query blocking, bf16 K/V ----------------
__global__ __launch_bounds__(256, 1) void k_attn_part(const float* __restrict__ Q,
        const ushort* __restrict__ Kp, const ushort* __restrict__ Vp,
        float* __restrict__ ps, float* __restrict__ pacc) {
    int head = blockIdx.y, chunk = blockIdx.z;
    int t = threadIdx.x;
    int wv = t >> 6, lane = t & 63;
    int qbase = (blockIdx.x * 4 + wv) * 4;
    float q[4][16];
    #pragma unroll
    for (int qq = 0; qq < 4; qq++) {
        int p = qbase + qq; if (p > 199) p = 199;
        const float4* qr = (const float4*)(Q + p * 128 + head * 16);
        #pragma unroll
        for (int u = 0; u < 4; u++) {
            float4 v = qr[u];
            q[qq][u * 4 + 0] = v.x * 0.25f; q[qq][u * 4 + 1] = v.y * 0.25f;
            q[qq][u * 4 + 2] = v.z * 0.25f; q[qq][u * 4 + 3] = v.w * 0.25f;
        }
    }
    const ushort* Kh = Kp + (size_t)head * HWSZ * 16;
    const ushort* Vh = Vp + (size_t)head * HWSZ * 16;
    float s[4] = {0.f, 0.f, 0.f, 0.f};
    float acc[4][16];
    #pragma unroll
    for (int qq = 0; qq < 4; qq++)
        #pragma unroll
        for (int i = 0; i < 16; i++) acc[qq][i] = 0.f;
    int k0 = chunk << 10;
    for (int kb = k0 + lane; kb < k0 + 1024; kb += 64) {
        const ush8* kr = reinterpret_cast<const ush8*>(Kh + (size_t)kb * 16);
        ush8 kA = kr[0], kB = kr[1];
        const ush8* vr = reinterpret_cast<const ush8*>(Vh + (size_t)kb * 16);
        ush8 vA = vr[0], vB = vr[1];
        float kk[16], vv[16];
        #pragma unroll
        for (int i = 0; i < 8; i++) {
            kk[i] = bf2f(kA[i]); kk[8 + i] = bf2f(kB[i]);
            vv[i] = bf2f(vA[i]); vv[8 + i] = bf2f(vB[i]);
        }
        #pragma unroll
        for (int qq = 0; qq < 4; qq++) {
            float l0 = fmaf(q[qq][3], kk[3], fmaf(q[qq][2], kk[2], fmaf(q[qq][1], kk[1], q[qq][0] * kk[0])));
            float l1 = fmaf(q[qq][7], kk[7], fmaf(q[qq][6], kk[6], fmaf(q[qq][5], kk[5], q[qq][4] * kk[4])));
            float l2 = fmaf(q[qq][11], kk[11], fmaf(q[qq][10], kk[10], fmaf(q[qq][9], kk[9], q[qq][8] * kk[8])));
            float l3 = fmaf(q[qq][15], kk[15], fmaf(q[qq][14], kk[14], fmaf(q[qq][13], kk[13], q[qq][12] * kk[12])));
            float e = __expf((l0 + l1) + (l2 + l3));
            s[qq] += e;
            #pragma unroll
            for (int i = 0; i < 16; i++) acc[qq][i] = fmaf(e, vv[i], acc[qq][i]);
        }
    }
    #pragma unroll
    for (int mask = 32; mask >= 1; mask >>= 1) {
        #pragma unroll
        for (int qq = 0; qq < 4; qq++) {
            s[qq] += __shfl_xor(s[qq], mask);
            #pragma unroll
            for (int i = 0; i < 16; i++) acc[qq][i] += __shfl_xor(acc[qq][i], mask);
        }
    }
    if (lane == 0) {
        #pragma unroll
        for (int qq = 0; qq < 4; qq++) {
            int p = qbase + qq;
            int idx = (chunk * 8 + head) * 208 + p;
            ps[idx] = s[qq];
            #pragma unroll
            for (int i = 0; i < 16; i++) pacc[idx * 16 + i] = acc[qq][i];
        }
    }
}
// combine: grid (200), 128 threads = 8 heads x 16 dims
__global__ __launch_bounds__(128) void k_attn_comb(const float* __restrict__ ps,
        const float* __restrict__ pacc, float* __restrict__ out) {
    int p = blockIdx.x;
    int t = threadIdx.x;
    int h = t >> 4, d = t & 15;
    float S = 0.f, A = 0.f;
    #pragma unroll
    for (int c = 0; c < 16; c++) {
        int idx = (c * 8 + h) * 208 + p;
        S += ps[idx];
        A += pacc[idx * 16 + d];
    }
    out[p * 128 + h * 16 + d] = A / S;
}

// ---------------- fused decoder tail: wo-GEMM + LN1 + FF1 + FF2 + LN2 ----------------
// grid (200), 128 threads; weights are L2-resident across blocks.
__global__ __launch_bounds__(128) void k_tail(const float* __restrict__ attno,
        const float* __restrict__ qf, const float* __restrict__ wo,
        const float* __restrict__ ln1_g, const float* __restrict__ ln1_b,
        const float* __restrict__ w_ff1, const float* __restrict__ b_ff1,
        const float* __restrict__ w_ff2, const float* __restrict__ b_ff2,
        const float* __restrict__ ln2_g, const float* __restrict__ ln2_b,
        float* __restrict__ h2out) {
    int p = blockIdx.x, d = threadIdx.x;
    __shared__ float att[128], h1s[128], fs[256], red[4];
    att[d] = attno[p * 128 + d];
    __syncthreads();
    float acc = 0.f;
    const float* wr = wo + d * 128;
    #pragma unroll 8
    for (int k = 0; k < 128; k++) acc = fmaf(wr[k], att[k], acc);
    float x = qf[p * 128 + d] + acc;
    // LN1
    float s = x;
    #pragma unroll
    for (int mask = 32; mask >= 1; mask >>= 1) s += __shfl_xor(s, mask);
    if ((d & 63) == 0) red[d >> 6] = s;
    __syncthreads();
    float mean = (red[0] + red[1]) * (1.f / 128.f);
    float dx = x - mean;
    float s2 = dx * dx;
    #pragma unroll
    for (int mask = 32; mask >= 1; mask >>= 1) s2 += __shfl_xor(s2, mask);
    if ((d & 63) == 0) red[2 + (d >> 6)] = s2;
    __syncthreads();
    float var = (red[2] + red[3]) * (1.f / 128.f);
    float h1v = dx * rsqrtf(var + 1e-5f) * ln1_g[d] + ln1_b[d];
    h1s[d] = h1v;
    __syncthreads();
    // FF1: j = d and j = d+128
    float a0 = 0.f, a1 = 0.f;
    const float* w1a = w_ff1 + d * 128;
    const float* w1b = w_ff1 + (d + 128) * 128;
    #pragma unroll 8
    for (int k = 0; k < 128; k++) {
        float hv = h1s[k];
        a0 = fmaf(w1a[k], hv, a0);
        a1 = fmaf(w1b[k], hv, a1);
    }
    fs[d] = fmaxf(a0 + b_ff1[d], 0.f);
    fs[d + 128] = fmaxf(a1 + b_ff1[d + 128], 0.f);
    __syncthreads();
    // FF2
    float a2 = 0.f;
    const float* w2 = w_ff2 + d * 256;
    #pragma unroll 8
    for (int j = 0; j < 256; j++) a2 = fmaf(w2[j], fs[j], a2);
    float x2 = h1v + a2 + b_ff2[d];
    // LN2
    __syncthreads();
    float t2 = x2;
    #pragma unroll
    for (int mask = 32; mask >= 1; mask >>= 1) t2 += __shfl_xor(t2, mask);
    if ((d & 63) == 0) red[d >> 6] = t2;
    __syncthreads();
    float mean2 = (red[0] + red[1]) * (1.f / 128.f);
    float dx2 = x2 - mean2;
    float v2 = dx2 * dx2;
    #pragma unroll
    for (int mask = 32; mask >= 1; mask >>= 1) v2 += __shfl_xor(v2, mask);
    if ((d & 63) == 0) red[2 + (d >> 6)] = v2;
    __syncthreads();
    float var2 = (red[2] + red[3]) * (1.f / 128.f);
    h2out[p * 128 + d] = dx2 * rsqrtf(var2 + 1e-5f) * ln2_g[d] + ln2_b[d];
}

// ---------------- prediction heads + score epilogue ----------------
__global__ void k_heads(const float* __restrict__ h2, const float* __restrict__ hm,
        const int* __restrict__ top_pos, const int* __restrict__ top_cls,
        const float* __restrict__ qpos,
        const float* __restrict__ w_hm, const float* __restrict__ b_hm,
        const float* __restrict__ w_rot, const float* __restrict__ b_rot,
        const float* __restrict__ w_dim, const float* __restrict__ b_dim,
        const float* __restrict__ w_center, const float* __restrict__ b_center,
        const float* __restrict__ w_height, const float* __restrict__ b_height,
        const float* __restrict__ w_vel, const float* __restrict__ b_vel,
        float* __restrict__ out) {
    int gid = blockIdx.x * 256 + threadIdx.x;
    if (gid >= 4000) return;
    int o = gid / 200, p = gid - o * 200;
    const float* wr; float bias;
    if (o < 10)      { wr = w_hm + o * 128;            bias = b_hm[o]; }
    else if (o < 12) { wr = w_rot + (o - 10) * 128;    bias = b_rot[o - 10]; }
    else if (o < 15) { wr = w_dim + (o - 12) * 128;    bias = b_dim[o - 12]; }
    else if (o < 17) { wr = w_center + (o - 15) * 128; bias = b_center[o - 15]; }
    else if (o < 18) { wr = w_height;                  bias = b_height[0]; }
    else             { wr = w_vel + (o - 18) * 128;    bias = b_vel[o - 18]; }
    const float* hr = h2 + p * 128;
    float dot = 0.f;
    #pragma unroll 8
    for (int d = 0; d < 128; d++) dot = fmaf(wr[d], hr[d], dot);
    dot += bias;
    float outv; int off;
    if (o < 10) {
        float qhs = hm[o * HWSZ + top_pos[p]];
        float oh = (top_cls[p] == o) ? 1.f : 0.f;
        outv = (1.f / (1.f + expf(-dot))) * qhs * oh;
        off = o * 200 + p;
    } else if (o < 12) { outv = dot; off = 2000 + (o - 10) * 200 + p; }
    else if (o < 15)   { outv = dot; off = 2400 + (o - 12) * 200 + p; }
    else if (o < 17)   { outv = dot + qpos[p * 2 + (o - 15)]; off = 3000 + (o - 15) * 200 + p; }
    else if (o < 18)   { outv = dot; off = 3400 + p; }
    else               { outv = dot; off = 3600 + (o - 18) * 200 + p; }
    out[off] = outv;
}

// ---------------- host ----------------
extern "C" void kernel_launch(void* const* d_in, const int* in_sizes, int n_in,
                              void* d_out, int out_size, void* d_ws, size_t ws_size,
                              hipStream_t stream) {
    const float* x        = (const float*)d_in[0];
    const float* w_shared = (const float*)d_in[1];
    const float* b_shared = (const float*)d_in[2];
    const float* w_heat   = (const float*)d_in[3];
    const float* b_heat   = (const float*)d_in[4];
    const float* w_ce     = (const float*)d_in[7];
    const float* b_ce     = (const float*)d_in[8];
    const float* w_qpos   = (const float*)d_in[9];
    const float* w_kpos   = (const float*)d_in[10];
    const float* wq       = (const float*)d_in[11];
    const float* wk       = (const float*)d_in[12];
    const float* wv       = (const float*)d_in[13];
    const float* wo       = (const float*)d_in[14];
    const float* ln1_g    = (const float*)d_in[15];
    const float* ln1_b    = (const float*)d_in[16];
    const float* ln2_g    = (const float*)d_in[17];
    const float* ln2_b    = (const float*)d_in[18];
    const float* w_ff1    = (const float*)d_in[19];
    const float* b_ff1    = (const float*)d_in[20];
    const float* w_ff2    = (const float*)d_in[21];
    const float* b_ff2    = (const float*)d_in[22];
    const float* w_center = (const float*)d_in[23];
    const float* b_center = (const float*)d_in[24];
    const float* w_height = (const float*)d_in[25];
    const float* b_height = (const float*)d_in[26];
    const float* w_dim    = (const float*)d_in[27];
    const float* b_dim    = (const float*)d_in[28];
    const float* w_rot    = (const float*)d_in[29];
    const float* b_rot    = (const float*)d_in[30];
    const float* w_vel    = (const float*)d_in[31];
    const float* b_vel    = (const float*)d_in[32];
    const float* w_hm     = (const float*)d_in[33];
    const float* b_hm     = (const float*)d_in[34];
    float* out = (float*)d_out;

    float* ws = (float*)d_ws;
    float* lidar = ws;                          // 2097152 f
    float* bigR  = lidar + 2097152;             // 8388608 f : xt_hi/xt_lo, later kvb/KpBh/VpBh
    ushort* xt_hi = (ushort*)bigR;              // 8388608 ushort
    ushort* xt_lo = xt_hi + 8388608;            // 8388608 ushort
    ushort* kvb  = (ushort*)bigR;               // bf16 [hw][128] (2097152 ush)
    ushort* KpBh = (ushort*)(bigR + 1048576);   // bf16 permuted K (2097152 ush)
    ushort* VpBh = (ushort*)(bigR + 2097152);   // bf16 permuted V (2097152 ush)
    float* wbh_f = bigR + 8388608;              // 294912 f
    float* wbl_f = wbh_f + 294912;              // 294912 f
    ushort* wb_hi = (ushort*)wbh_f;
    ushort* wb_lo = (ushort*)wbl_f;
    float* wt2   = wbl_f + 294912;              // 18432
    float* sig   = wt2 + 18432;                 // 163840
    float* hmb   = sig + 163840;                // 163840
    unsigned* hist_hi = (unsigned*)(hmb + 163840);   // 65536
    unsigned* hist_lo = hist_hi + 65536;        // 65536
    unsigned* state   = hist_lo + 65536;        // 64
    unsigned* cnts    = state + 64;             // 64
    unsigned* ck      = cnts + 64;              // 256
    unsigned* ci      = ck + 256;               // 256
    unsigned* ti      = ci + 256;               // 8192
    int* top_pos      = (int*)(ti + 8192);      // 256
    int* top_cls      = top_pos + 256;          // 256
    float* qpos  = (float*)(top_cls + 256);     // 512
    float* qf    = qpos + 512;                  // 25600
    float* qin   = qf + 25600;                  // 25600
    float* qbuf  = qin + 25600;                 // 25600
    float* attno = qbuf + 25600;                // 25600
    float* h2    = attno + 25600;               // 25600
    float* ps_b  = h2 + 25600;                  // 26624 (16*8*208)
    float* pacc_b = ps_b + 26624;               // 425984 (16*8*208*16)
    ushort* wkb  = (ushort*)(pacc_b + 425984);  // 16384 ush
    ushort* wvb  = wkb + 16384;                 // 16384 ush
    size_t needed = (size_t)((pacc_b + 425984 + 16384) - ws) * sizeof(float);
    if (ws_size < needed) return;

    k_prep_w2<<<72, 256, 0, stream>>>(w_heat, wt2);
    k_cvt_w<<<2304, 256, 0, stream>>>(w_shared, wb_hi, wb_lo);
    k_cvt_w128<<<64, 256, 0, stream>>>(wk, wv, wkb, wvb);
    k_cvt_x<<<dim3(256, 8), 256, 0, stream>>>(x, xt_hi, xt_lo);
    k_conv1_mfma<<<256, 256, 0, stream>>>(xt_hi, xt_lo, wb_hi, wb_lo, b_shared, lidar);
    k_conv2<<<256, 256, 0, stream>>>(lidar, wt2, b_heat, sig);
    hipMemsetAsync(hist_hi, 0, (65536u * 2 + 128) * sizeof(unsigned), stream);
    k_nms<<<640, 256, 0, stream>>>(sig, hmb, hist_hi);
    k_scan_hi<<<1, 256, 0, stream>>>(hist_hi, state);
    k_hist_lo<<<640, 256, 0, stream>>>(hmb, state, hist_lo);
    k_scan_lo<<<1, 256, 0, stream>>>(hist_lo, state);
    k_collect<<<640, 256, 0, stream>>>(hmb, state, ck, ci, ti, cnts);
    k_topk_final<<<1, 256, 0, stream>>>(state, cnts, ck, ci, ti, top_pos, top_cls);
    k_gather<<<100, 256, 0, stream>>>(lidar, top_pos, top_cls, w_ce, b_ce, w_qpos, qf, qin, qpos);
    k_kvin<<<256, 256, 0, stream>>>(lidar, w_kpos, kvb);
    k_gemm<0><<<dim3(4, 2), 256, 0, stream>>>(qin, wq, qbuf, 200, 128, 128, nullptr, nullptr);
    k_gemm_kv<<<256, 256, 0, stream>>>(kvb, wkb, KpBh);
    k_gemm_kv<<<256, 256, 0, stream>>>(kvb, wvb, VpBh);
    k_attn_part<<<dim3(13, 8, 16), 256, 0, stream>>>(qbuf, KpBh, VpBh, ps_b, pacc_b);
    k_attn_comb<<<200, 128, 0, stream>>>(ps_b, pacc_b, attno);
    k_tail<<<200, 128, 0, stream>>>(attno, qf, wo, ln1_g, ln1_b,
        w_ff1, b_ff1, w_ff2, b_ff2, ln2_g, ln2_b, h2);
    k_heads<<<16, 256, 0, stream>>>(h2, hmb, top_pos, top_cls, qpos,
        w_hm, b_hm, w_rot, b_rot, w_dim, b_dim, w_center, b_center,
        w_height, b_height, w_vel, b_vel, out);
}

// Round 9
// 487.940 us; speedup vs baseline: 1.3650x; 1.0181x over previous
//
#include <hip/hip_runtime.h>
#include <math.h>

#define HWSZ 16384

typedef __attribute__((ext_vector_type(8))) short short8;
typedef __attribute__((ext_vector_type(8))) unsigned short ush8;
typedef __attribute__((ext_vector_type(4))) float f4;
typedef __attribute__((ext_vector_type(16))) float f16x;

__device__ __forceinline__ ushort f2bf(float f) {
    unsigned u = __float_as_uint(f);
    return (ushort)((u + 0x7fffu + ((u >> 16) & 1u)) >> 16);
}
__device__ __forceinline__ float bf2f(ushort b) {
    return __uint_as_float(((unsigned)b) << 16);
}

// ---------------- weight prep ----------------
__global__ void k_prep_w2(const float* __restrict__ w, float* __restrict__ wt) {
    int idx = blockIdx.x * 256 + threadIdx.x;        // 1152*16
    if (idx >= 1152 * 16) return;
    int k = idx >> 4, oc = idx & 15;
    wt[idx] = (oc < 10) ? w[oc * 1152 + k] : 0.f;
}
// w_shared [oc][c][kh][kw] -> [oc][tap][c] bf16 hi/lo
__global__ void k_cvt_w(const float* __restrict__ w, ushort* __restrict__ wh,
                        ushort* __restrict__ wl) {
    int idx = blockIdx.x * 256 + threadIdx.x;   // 589824
    if (idx >= 589824) return;
    int oc = idx / 4608, r = idx - oc * 4608;
    int tap = r >> 9, c = r & 511;
    float f = w[oc * 4608 + c * 9 + tap];
    ushort hb = f2bf(f);
    wh[idx] = hb;
    wl[idx] = f2bf(f - bf2f(hb));
}
// wk, wv [128][128] fp32 -> bf16
__global__ void k_cvt_w128(const float* __restrict__ a, const float* __restrict__ b,
                           ushort* __restrict__ oa, ushort* __restrict__ ob) {
    int i = blockIdx.x * 256 + threadIdx.x;     // 16384
    if (i < 16384) { oa[i] = f2bf(a[i]); ob[i] = f2bf(b[i]); }
}
// x [c][hw] fp32 -> xt_hi/xt_lo [hw][c] bf16
__global__ __launch_bounds__(256) void k_cvt_x(const float* __restrict__ x,
        ushort* __restrict__ xh, ushort* __restrict__ xl) {
    __shared__ float T[64 * 65];
    int hw0 = blockIdx.x << 6;
    int c0 = blockIdx.y << 6;
    int t = threadIdx.x;
    {
        int cl = t >> 2, q = t & 3;
        const float* src = x + (size_t)(c0 + cl) * HWSZ + hw0 + q * 16;
        #pragma unroll
        for (int k = 0; k < 4; k++) {
            float4 v = *reinterpret_cast<const float4*>(src + k * 4);
            float* dst = &T[cl * 65 + q * 16 + k * 4];
            dst[0] = v.x; dst[1] = v.y; dst[2] = v.z; dst[3] = v.w;
        }
    }
    __syncthreads();
    {
        int hwl = t >> 2, q = t & 3;
        int cc = q * 16;
        size_t ob = (size_t)(hw0 + hwl) * 512 + c0 + cc;
        #pragma unroll
        for (int half = 0; half < 2; half++) {
            ush8 hv, lv;
            #pragma unroll
            for (int k = 0; k < 8; k++) {
                float f = T[(cc + half * 8 + k) * 65 + hwl];
                ushort hb = f2bf(f);
                hv[k] = hb;
                lv[k] = f2bf(f - bf2f(hb));
            }
            *reinterpret_cast<ush8*>(xh + ob + half * 8) = hv;
            *reinterpret_cast<ush8*>(xl + ob + half * 8) = lv;
        }
    }
}

// ---------------- conv1 via MFMA bf16 3-term split ----------------
// LDS row stride 36 ushorts (18 dwords, gcd(18,32)=2 -> 2-way bank alias = free;
// old stride 40 = 20 dw, gcd 4 -> 4-way, cost 1.42e7 conflict cycles)
__global__ __launch_bounds__(256) void k_conv1_mfma(
        const ushort* __restrict__ xh, const ushort* __restrict__ xl,
        const ushort* __restrict__ wh, const ushort* __restrict__ wl,
        const float* __restrict__ bias, float* __restrict__ out) {
    // A: [buf][plane][64][36] @ buf*4608 + plane*2304
    // B: [buf][plane][128][36] @ 9216 + buf*9216 + plane*4608
    __shared__ ushort smem[27648];   // 55296 B
    const int t = threadIdx.x;
    const int h = blockIdx.x >> 1, w0 = (blockIdx.x & 1) << 6;
    const int l = t & 63;
    const int wid = t >> 6;
    const int wm = wid >> 1, wn = wid & 1;
    const int l15 = l & 15, lhi = l >> 4;
    const int arow = t >> 2, achk = t & 3;

    f4 acc[2][4];
    #pragma unroll
    for (int m = 0; m < 2; m++)
        #pragma unroll
        for (int n = 0; n < 4; n++) acc[m][n] = (f4){0.f, 0.f, 0.f, 0.f};

    short8 rA[2], rB[2][2];
    const short8 zz = {0, 0, 0, 0, 0, 0, 0, 0};

    auto issue = [&](int it) {
        int c0 = (it / 9) << 5;
        int tap = it % 9;
        int dh = tap / 3 - 1, dw = tap % 3 - 1;
        int hh = h + dh;
        int wg = w0 + arow + dw;
        if (hh >= 0 && hh < 128 && wg >= 0 && wg < 128) {
            size_t off = ((size_t)(hh * 128 + wg) << 9) + c0 + (achk << 3);
            rA[0] = *reinterpret_cast<const short8*>(xh + off);
            rA[1] = *reinterpret_cast<const short8*>(xl + off);
        } else { rA[0] = zz; rA[1] = zz; }
        #pragma unroll
        for (int u = 0; u < 2; u++) {
            int oc = (u << 6) + (t >> 2);
            size_t off = (size_t)oc * 4608 + tap * 512 + c0 + (achk << 3);
            rB[u][0] = *reinterpret_cast<const short8*>(wh + off);
            rB[u][1] = *reinterpret_cast<const short8*>(wl + off);
        }
    };
    auto wstage = [&](int buf) {
        *reinterpret_cast<short8*>(&smem[buf * 4608 + arow * 36 + achk * 8]) = rA[0];
        *reinterpret_cast<short8*>(&smem[buf * 4608 + 2304 + arow * 36 + achk * 8]) = rA[1];
        #pragma unroll
        for (int u = 0; u < 2; u++) {
            int oc = (u << 6) + (t >> 2);
            *reinterpret_cast<short8*>(&smem[9216 + buf * 9216 + oc * 36 + achk * 8]) = rB[u][0];
            *reinterpret_cast<short8*>(&smem[9216 + buf * 9216 + 4608 + oc * 36 + achk * 8]) = rB[u][1];
        }
    };

    issue(0);
    wstage(0);
    issue(1);
    __syncthreads();

    for (int it = 0; it < 144; ++it) {
        int buf = it & 1;
        short8 aH[2], aL[2], bH[4], bL[4];
        #pragma unroll
        for (int m = 0; m < 2; m++) {
            int row = wm * 32 + m * 16 + l15;
            aH[m] = *reinterpret_cast<const short8*>(&smem[buf * 4608 + row * 36 + lhi * 8]);
            aL[m] = *reinterpret_cast<const short8*>(&smem[buf * 4608 + 2304 + row * 36 + lhi * 8]);
        }
        #pragma unroll
        for (int n = 0; n < 4; n++) {
            int oc = wn * 64 + n * 16 + l15;
            bH[n] = *reinterpret_cast<const short8*>(&smem[9216 + buf * 9216 + oc * 36 + lhi * 8]);
            bL[n] = *reinterpret_cast<const short8*>(&smem[9216 + buf * 9216 + 4608 + oc * 36 + lhi * 8]);
        }
        #pragma unroll
        for (int m = 0; m < 2; m++)
            #pragma unroll
            for (int n = 0; n < 4; n++) {
                acc[m][n] = __builtin_amdgcn_mfma_f32_16x16x32_bf16(aH[m], bH[n], acc[m][n], 0, 0, 0);
                acc[m][n] = __builtin_amdgcn_mfma_f32_16x16x32_bf16(aL[m], bH[n], acc[m][n], 0, 0, 0);
                acc[m][n] = __builtin_amdgcn_mfma_f32_16x16x32_bf16(aH[m], bL[n], acc[m][n], 0, 0, 0);
            }
        if (it + 1 < 144) {
            wstage(buf ^ 1);
            if (it + 2 < 144) issue(it + 2);
        }
        __syncthreads();
    }

    // epilogue: bias+relu, transpose through LDS, coalesced [oc][hw] store
    float* ot = reinterpret_cast<float*>(smem);   // [64][132] floats = 33792 B <= 55296 B
    #pragma unroll
    for (int m = 0; m < 2; m++)
        #pragma unroll
        for (int n = 0; n < 4; n++) {
            int oc = wn * 64 + n * 16 + l15;
            float b = bias[oc];
            #pragma unroll
            for (int r = 0; r < 4; r++) {
                int px = wm * 32 + m * 16 + lhi * 4 + r;
                ot[px * 132 + oc] = fmaxf(acc[m][n][r] + b, 0.f);
            }
        }
    __syncthreads();
    {
        int oc = t >> 1, half = t & 1;
        int base = h * 128 + w0 + half * 32;
        #pragma unroll
        for (int i = 0; i < 32; i += 4) {
            float4 v;
            v.x = ot[(half * 32 + i + 0) * 132 + oc];
            v.y = ot[(half * 32 + i + 1) * 132 + oc];
            v.z = ot[(half * 32 + i + 2) * 132 + oc];
            v.w = ot[(half * 32 + i + 3) * 132 + oc];
            *reinterpret_cast<float4*>(&out[(size_t)oc * HWSZ + base + i]) = v;
        }
    }
}

// ---------------- conv2: 128->10(pad16) 3x3 + bias + sigmoid ----------------
__global__ __launch_bounds__(256) void k_conv2(const float* __restrict__ lidar,
        const float* __restrict__ wt, const float* __restrict__ bias,
        float* __restrict__ sig) {
    __shared__ float xs[16 * 3 * 68];
    __shared__ float wsm[144 * 16];
    int bid = blockIdx.x;
    int h = bid >> 1, w0 = (bid & 1) << 6;
    int t = threadIdx.x;
    int tpx = (t & 15) << 2;
    int oc = t >> 4;                // 0..15 (10 real)
    float acc[4] = {0.f, 0.f, 0.f, 0.f};
    for (int c0 = 0; c0 < 128; c0 += 16) {
        for (int i = t; i < 16 * 3 * 66; i += 256) {
            int c = i / 198; int rem = i - c * 198; int r = rem / 66; int j = rem - r * 66;
            int gr = h - 1 + r, gc = w0 - 1 + j;
            float v = 0.f;
            if (((unsigned)gr < 128u) & ((unsigned)gc < 128u))
                v = lidar[(c0 + c) * HWSZ + gr * 128 + gc];
            xs[(c * 3 + r) * 68 + j] = v;
        }
        {
            const float4* src = (const float4*)(wt + c0 * 9 * 16);
            float4* dst = (float4*)wsm;
            for (int i = t; i < 576; i += 256) dst[i] = src[i];
        }
        __syncthreads();
        #pragma unroll 4
        for (int c = 0; c < 16; c++) {
            #pragma unroll
            for (int kh = 0; kh < 3; kh++) {
                const float* xr = &xs[(c * 3 + kh) * 68 + tpx];
                float xv0 = xr[0], xv1 = xr[1], xv2 = xr[2], xv3 = xr[3], xv4 = xr[4], xv5 = xr[5];
                #pragma unroll
                for (int kw = 0; kw < 3; kw++) {
                    float wv = wsm[(c * 9 + kh * 3 + kw) * 16 + oc];
                    float p0 = (kw == 0) ? xv0 : ((kw == 1) ? xv1 : xv2);
                    float p1 = (kw == 0) ? xv1 : ((kw == 1) ? xv2 : xv3);
                    float p2 = (kw == 0) ? xv2 : ((kw == 1) ? xv3 : xv4);
                    float p3 = (kw == 0) ? xv3 : ((kw == 1) ? xv4 : xv5);
                    acc[0] += p0 * wv; acc[1] += p1 * wv; acc[2] += p2 * wv; acc[3] += p3 * wv;
                }
            }
        }
        __syncthreads();
    }
    if (oc < 10) {
        float b = bias[oc];
        int col = h * 128 + w0 + tpx;
        float4 v;
        v.x = 1.f / (1.f + expf(-(acc[0] + b)));
        v.y = 1.f / (1.f + expf(-(acc[1] + b)));
        v.z = 1.f / (1.f + expf(-(acc[2] + b)));
        v.w = 1.f / (1.f + expf(-(acc[3] + b)));
        *(float4*)&sig[oc * HWSZ + col] = v;
    }
}

// ---------------- 3x3 local-max NMS + fused hi-histogram ----------------
__global__ void k_nms(const float* __restrict__ sig, float* __restrict__ hm,
                      unsigned* __restrict__ hist) {
    int gid = blockIdx.x * 256 + threadIdx.x;   // 163840
    int c = gid >> 14, i = gid & 16383;
    int h = i >> 7, w = i & 127;
    float v = sig[gid];
    float keep = 0.f;
    if (c >= 8) keep = v;
    else if (h >= 1 && h <= 126 && w >= 1 && w <= 126) {
        const float* s = sig + c * HWSZ;
        float m = v;
        #pragma unroll
        for (int dh = -1; dh <= 1; dh++)
            #pragma unroll
            for (int dw = -1; dw <= 1; dw++)
                m = fmaxf(m, s[(h + dh) * 128 + (w + dw)]);
        keep = (v == m) ? v : 0.f;
    }
    hm[gid] = keep;
    unsigned kb = __float_as_uint(keep);
    if (kb) atomicAdd(&hist[kb >> 16], 1u);
}

// ---------------- exact top-200 radix select ----------------
__global__ void k_scan_hi(const unsigned* __restrict__ hist, unsigned* __restrict__ state) {
    __shared__ unsigned ps[256];
    __shared__ int selc;
    __shared__ unsigned selcum;
    __shared__ unsigned cb[256];
    int t = threadIdx.x;
    unsigned s = 0;
    const uint4* hp = reinterpret_cast<const uint4*>(hist + t * 256);
    for (int i = 0; i < 64; i++) { uint4 v = hp[i]; s += v.x + v.y + v.z + v.w; }
    ps[t] = s;
    __syncthreads();
    if (t == 0) {
        unsigned cum = 0; int c = 255;
        for (; c > 0; c--) { if (cum + ps[c] >= 200u) break; cum += ps[c]; }
        selc = c; selcum = cum;
    }
    __syncthreads();
    int c = selc;
    cb[t] = hist[c * 256 + t];
    __syncthreads();
    if (t == 0) {
        unsigned cum = selcum; int b = 255;
        for (; b > 0; b--) { if (cum + cb[b] >= 200u) break; cum += cb[b]; }
        state[8] = (unsigned)(c * 256 + b);   // b*
        state[9] = 200u - cum;                // K'
        state[10] = cum;                      // count strictly above bin b*
    }
}
__global__ void k_hist_lo(const float* __restrict__ hm, const unsigned* __restrict__ state,
                          unsigned* __restrict__ hist) {
    int gid = blockIdx.x * 256 + threadIdx.x;
    unsigned k = __float_as_uint(hm[gid]);
    if (k && (k >> 16) == state[8]) atomicAdd(&hist[k & 0xFFFFu], 1u);
}
__global__ void k_scan_lo(const unsigned* __restrict__ hist, unsigned* __restrict__ state) {
    __shared__ unsigned ps[256];
    __shared__ int selc;
    __shared__ unsigned selcum;
    __shared__ unsigned cb[256];
    int t = threadIdx.x;
    unsigned target = state[9];
    unsigned s = 0;
    const uint4* hp = reinterpret_cast<const uint4*>(hist + t * 256);
    for (int i = 0; i < 64; i++) { uint4 v = hp[i]; s += v.x + v.y + v.z + v.w; }
    ps[t] = s;
    __syncthreads();
    if (t == 0) {
        unsigned cum = 0; int c = 255;
        for (; c > 0; c--) { if (cum + ps[c] >= target) break; cum += ps[c]; }
        selc = c; selcum = cum;
    }
    __syncthreads();
    int c = selc;
    cb[t] = hist[c * 256 + t];
    __syncthreads();
    if (t == 0) {
        unsigned cum = selcum; int b = 255;
        for (; b > 0; b--) { if (cum + cb[b] >= target) break; cum += cb[b]; }
        unsigned lstar = (unsigned)(c * 256 + b);
        state[2] = (state[8] << 16) | lstar;  // key*
        state[0] = state[10] + cum;           // C_gt
        state[1] = target - cum;              // need_eq ties
    }
}
__global__ void k_collect(const float* __restrict__ hm, const unsigned* __restrict__ state,
        unsigned* __restrict__ ck, unsigned* __restrict__ ci,
        unsigned* __restrict__ ti, unsigned* __restrict__ cnts) {
    int gid = blockIdx.x * 256 + threadIdx.x;
    unsigned k = __float_as_uint(hm[gid]);
    unsigned ks = state[2];
    if (k > ks) {
        unsigned pos = atomicAdd(&cnts[0], 1u);
        if (pos < 256u) { ck[pos] = k; ci[pos] = (unsigned)gid; }
    } else if (k == ks) {
        unsigned pos = atomicAdd(&cnts[1], 1u);
        if (pos < 8192u) ti[pos] = (unsigned)gid;
    }
}
__global__ void k_topk_final(const unsigned* __restrict__ state, const unsigned* __restrict__ cnts,
        const unsigned* __restrict__ ck, const unsigned* __restrict__ ci,
        const unsigned* __restrict__ ti, int* __restrict__ top_pos, int* __restrict__ top_cls) {
    __shared__ unsigned kk[200], ii[200];
    int t = threadIdx.x;
    unsigned cgt = cnts[0];
    unsigned need = state[1];
    unsigned keystar = state[2];
    unsigned cntEq = cnts[1]; if (cntEq > 8192u) cntEq = 8192u;
    if ((unsigned)t < cgt && t < 200) { kk[t] = ck[t]; ii[t] = ci[t]; }
    for (unsigned e = t; e < cntEq; e += 256) {
        unsigned my = ti[e]; unsigned r = 0;
        for (unsigned j = 0; j < cntEq; j++) r += (ti[j] < my);
        if (r < need) { kk[cgt + r] = keystar; ii[cgt + r] = my; }
    }
    __syncthreads();
    if (t < 200) {
        unsigned mk = kk[t], mi = ii[t]; int r = 0;
        for (int j = 0; j < 200; j++) {
            unsigned ok = kk[j], oi = ii[j];
            r += (ok > mk) || (ok == mk && oi < mi);
        }
        top_cls[r] = (int)(mi >> 14);
        top_pos[r] = (int)(mi & 16383u);
    }
}

// ---------------- gather + class encoding + q_in ----------------
__global__ void k_gather(const float* __restrict__ lidar, const int* __restrict__ top_pos,
        const int* __restrict__ top_cls, const float* __restrict__ w_ce,
        const float* __restrict__ b_ce, const float* __restrict__ w_qpos,
        float* __restrict__ qf, float* __restrict__ qin, float* __restrict__ qpos) {
    int gid = blockIdx.x * 256 + threadIdx.x;   // 200*128
    if (gid >= 200 * 128) return;
    int p = gid >> 7, d = gid & 127;
    int idx = top_pos[p], cls = top_cls[p];
    float px = (float)(idx & 127) + 0.5f, py = (float)(idx >> 7) + 0.5f;
    float v = lidar[d * HWSZ + idx] + w_ce[d * 10 + cls] + b_ce[d];
    qf[gid] = v;
    qin[gid] = v + px * w_qpos[d * 2] + py * w_qpos[d * 2 + 1];
    if (d < 2) qpos[p * 2 + d] = (d == 0) ? px : py;
}

// ---------------- kv_in = lidar^T + bev_pos @ w_kpos^T -> bf16 [hw][128] ----------------
__global__ __launch_bounds__(256) void k_kvin(const float* __restrict__ lidar,
        const float* __restrict__ w_kpos, ushort* __restrict__ kv) {
    __shared__ float T[128 * 65];
    int hw0 = blockIdx.x << 6;
    int t = threadIdx.x;
    for (int i = t; i < 128 * 64; i += 256) {
        int d = i >> 6, c = i & 63;
        T[d * 65 + c] = lidar[d * HWSZ + hw0 + c];
    }
    __syncthreads();
    for (int i = t; i < 64 * 128; i += 256) {
        int r = i >> 7, d = i & 127;
        int hw = hw0 + r;
        float bx = (float)(hw & 127) + 0.5f, by = (float)(hw >> 7) + 0.5f;
        kv[(size_t)hw * 128 + d] = f2bf(T[d * 65 + r] + bx * w_kpos[d * 2] + by * w_kpos[d * 2 + 1]);
    }
}

// ---------------- K/V projection: bf16 MFMA GEMM, bf16 permuted store ----------------
__global__ __launch_bounds__(256) void k_gemm_kv(const ushort* __restrict__ A,
        const ushort* __restrict__ B, ushort* __restrict__ C) {
    __shared__ ushort As[64 * 136];     // 17408 B
    __shared__ ushort Bs[128 * 136];    // 34816 B
    int m0 = blockIdx.x << 6;
    int t = threadIdx.x;
    {
        int r = t >> 3, c = (t & 7) << 4;
        #pragma unroll
        for (int p = 0; p < 2; p++) {
            int row = p * 32 + r;
            const ush8* src = reinterpret_cast<const ush8*>(A + (size_t)(m0 + row) * 128 + c);
            *reinterpret_cast<ush8*>(&As[row * 136 + c]) = src[0];
            *reinterpret_cast<ush8*>(&As[row * 136 + c + 8]) = src[1];
        }
        #pragma unroll
        for (int p = 0; p < 4; p++) {
            int row = p * 32 + r;
            const ush8* src = reinterpret_cast<const ush8*>(B + (size_t)row * 128 + c);
            *reinterpret_cast<ush8*>(&Bs[row * 136 + c]) = src[0];
            *reinterpret_cast<ush8*>(&Bs[row * 136 + c + 8]) = src[1];
        }
    }
    __syncthreads();
    int l = t & 63, wid = t >> 6;
    int wm = wid >> 1, wn = wid & 1;
    int l31 = l & 31, lk = l >> 5;
    f16x acc[2];
    #pragma unroll
    for (int n = 0; n < 2; n++)
        #pragma unroll
        for (int i = 0; i < 16; i++) acc[n][i] = 0.f;
    #pragma unroll
    for (int ks = 0; ks < 8; ks++) {
        short8 aF = *reinterpret_cast<const short8*>(&As[(wm * 32 + l31) * 136 + ks * 16 + lk * 8]);
        #pragma unroll
        for (int n = 0; n < 2; n++) {
            short8 bF = *reinterpret_cast<const short8*>(&Bs[(wn * 64 + n * 32 + l31) * 136 + ks * 16 + lk * 8]);
            acc[n] = __builtin_amdgcn_mfma_f32_32x32x16_bf16(aF, bF, acc[n], 0, 0, 0);
        }
    }
    #pragma unroll
    for (int n = 0; n < 2; n++) {
        int oc = wn * 64 + n * 32 + l31;
        size_t cb = (size_t)(oc >> 4) * HWSZ * 16 + (oc & 15);
        #pragma unroll
        for (int r = 0; r < 16; r++) {
            int mrow = wm * 32 + (r & 3) + ((r >> 2) << 3) + (lk << 2);
            C[cb + (size_t)(m0 + mrow) * 16] = f2bf(acc[n][r]);
        }
    }
}

// ---------------- tiled fp32 GEMM  C[M,N] = A[M,K] * B[N,K]^T (EPI 0 only used) ----------------
template<int EPI>
__global__ __launch_bounds__(256) void k_gemm(const float* __restrict__ A,
        const float* __restrict__ B, float* __restrict__ C, int M, int N, int K,
        const float* __restrict__ bias, const float* __restrict__ res) {
    __shared__ float As[16 * 68];
    __shared__ float Bs[16 * 68];
    int m0 = blockIdx.x * 64, n0 = blockIdx.y * 64;
    int t = threadIdx.x;
    int mi = (t & 15) << 2, ni = (t >> 4) << 2;
    float acc[4][4];
    #pragma unroll
    for (int i = 0; i < 4; i++)
        #pragma unroll
        for (int j = 0; j < 4; j++) acc[i][j] = 0.f;
    int r = t >> 2, kq = (t & 3) << 2;
    for (int k0 = 0; k0 < K; k0 += 16) {
        float4 v = make_float4(0.f, 0.f, 0.f, 0.f);
        if (m0 + r < M) v = *(const float4*)&A[(m0 + r) * K + k0 + kq];
        As[(kq + 0) * 68 + r] = v.x; As[(kq + 1) * 68 + r] = v.y;
        As[(kq + 2) * 68 + r] = v.z; As[(kq + 3) * 68 + r] = v.w;
        float4 w = *(const float4*)&B[(n0 + r) * K + k0 + kq];
        Bs[(kq + 0) * 68 + r] = w.x; Bs[(kq + 1) * 68 + r] = w.y;
        Bs[(kq + 2) * 68 + r] = w.z; Bs[(kq + 3) * 68 + r] = w.w;
        __syncthreads();
        #pragma unroll
        for (int k = 0; k < 16; k++) {
            float4 a = *(const float4*)&As[k * 68 + mi];
            float4 b = *(const float4*)&Bs[k * 68 + ni];
            acc[0][0] += a.x * b.x; acc[0][1] += a.x * b.y; acc[0][2] += a.x * b.z; acc[0][3] += a.x * b.w;
            acc[1][0] += a.y * b.x; acc[1][1] += a.y * b.y; acc[1][2] += a.y * b.z; acc[1][3] += a.y * b.w;
            acc[2][0] += a.z * b.x; acc[2][1] += a.z * b.y; acc[2][2] += a.z * b.z; acc[2][3] += a.z * b.w;
            acc[3][0] += a.w * b.x; acc[3][1] += a.w * b.y; acc[3][2] += a.w * b.z; acc[3][3] += a.w * b.w;
        }
        __syncthreads();
    }
    #pragma unroll
    for (int i = 0; i < 4; i++) {
        int m = m0 + mi + i;
        if (m >= M) continue;
        #pragma unroll
        for (int j = 0; j < 4; j++) {
            int n = n0 + ni + j;
            float v = acc[i][j];
            if (EPI == 2) v = fmaxf(v + bias[n], 0.f);
            if (EPI == 3) v += bias[n] + res[m * N + n];
            C[m * N + n] = v;
        }
    }
}

// ---------------- split-K flash attention, 4-query blocking, bf16 K/V ----------------
__global__ __launch_bounds__(256, 1) void k_attn_part(const float* __restrict__ Q,
        const ushort* __restrict__ Kp, const ushort* __restrict__ Vp,
        float* __restrict__ ps, float* __restrict__ pacc) {
    int head = blockIdx.y, chunk = blockIdx.z;
    int t = threadIdx.x;
    int wv = t >> 6, lane = t & 63;
    int qbase = (blockIdx.x * 4 + wv) * 4;
    float q[4][16];
    #pragma unroll
    for (int qq = 0; qq < 4; qq++) {
        int p = qbase + qq; if (p > 199) p = 199;
        const float4* qr = (const float4*)(Q + p * 128 + head * 16);
        #pragma unroll
        for (int u = 0; u < 4; u++) {
            float4 v = qr[u];
            q[qq][u * 4 + 0] = v.x * 0.25f; q[qq][u * 4 + 1] = v.y * 0.25f;
            q[qq][u * 4 + 2] = v.z * 0.25f; q[qq][u * 4 + 3] = v.w * 0.25f;
        }
    }
    const ushort* Kh = Kp + (size_t)head * HWSZ * 16;
    const ushort* Vh = Vp + (size_t)head * HWSZ * 16;
    float s[4] = {0.f, 0.f, 0.f, 0.f};
    float acc[4][16];
    #pragma unroll
    for (int qq = 0; qq < 4; qq++)
        #pragma unroll
        for (int i = 0; i < 16; i++) acc[qq][i] = 0.f;
    int k0 = chunk << 10;
    for (int kb = k0 + lane; kb < k0 + 1024; kb += 64) {
        const ush8* kr = reinterpret_cast<const ush8*>(Kh + (size_t)kb * 16);
        ush8 kA = kr[0], kB = kr[1];
        const ush8* vr = reinterpret_cast<const ush8*>(Vh + (size_t)kb * 16);
        ush8 vA = vr[0], vB = vr[1];
        float kk[16], vv[16];
        #pragma unroll
        for (int i = 0; i < 8; i++) {
            kk[i] = bf2f(kA[i]); kk[8 + i] = bf2f(kB[i]);
            vv[i] = bf2f(vA[i]); vv[8 + i] = bf2f(vB[i]);
        }
        #pragma unroll
        for (int qq = 0; qq < 4; qq++) {
            float l0 = fmaf(q[qq][3], kk[3], fmaf(q[qq][2], kk[2], fmaf(q[qq][1], kk[1], q[qq][0] * kk[0])));
            float l1 = fmaf(q[qq][7], kk[7], fmaf(q[qq][6], kk[6], fmaf(q[qq][5], kk[5], q[qq][4] * kk[4])));
            float l2 = fmaf(q[qq][11], kk[11], fmaf(q[qq][10], kk[10], fmaf(q[qq][9], kk[9], q[qq][8] * kk[8])));
            float l3 = fmaf(q[qq][15], kk[15], fmaf(q[qq][14], kk[14], fmaf(q[qq][13], kk[13], q[qq][12] * kk[12])));
            float e = __expf((l0 + l1) + (l2 + l3));
            s[qq] += e;
            #pragma unroll
            for (int i = 0; i < 16; i++) acc[qq][i] = fmaf(e, vv[i], acc[qq][i]);
        }
    }
    #pragma unroll
    for (int mask = 32; mask >= 1; mask >>= 1) {
        #pragma unroll
        for (int qq = 0; qq < 4; qq++) {
            s[qq] += __shfl_xor(s[qq], mask);
            #pragma unroll
            for (int i = 0; i < 16; i++) acc[qq][i] += __shfl_xor(acc[qq][i], mask);
        }
    }
    if (lane == 0) {
        #pragma unroll
        for (int qq = 0; qq < 4; qq++) {
            int p = qbase + qq;
            int idx = (chunk * 8 + head) * 208 + p;
            ps[idx] = s[qq];
            #pragma unroll
            for (int i = 0; i < 16; i++) pacc[idx * 16 + i] = acc[qq][i];
        }
    }
}
// combine: grid (200), 128 threads = 8 heads x 16 dims
__global__ __launch_bounds__(128) void k_attn_comb(const float* __restrict__ ps,
        const float* __restrict__ pacc, float* __restrict__ out) {
    int p = blockIdx.x;
    int t = threadIdx.x;
    int h = t >> 4, d = t & 15;
    float S = 0.f, A = 0.f;
    #pragma unroll
    for (int c = 0; c < 16; c++) {
        int idx = (c * 8 + h) * 208 + p;
        S += ps[idx];
        A += pacc[idx * 16 + d];
    }
    out[p * 128 + h * 16 + d] = A / S;
}

// ---------------- fused decoder tail: wo-GEMM + LN1 + FF1 + FF2 + LN2 ----------------
__global__ __launch_bounds__(128) void k_tail(const float* __restrict__ attno,
        const float* __restrict__ qf, const float* __restrict__ wo,
        const float* __restrict__ ln1_g, const float* __restrict__ ln1_b,
        const float* __restrict__ w_ff1, const float* __restrict__ b_ff1,
        const float* __restrict__ w_ff2, const float* __restrict__ b_ff2,
        const float* __restrict__ ln2_g, const float* __restrict__ ln2_b,
        float* __restrict__ h2out) {
    int p = blockIdx.x, d = threadIdx.x;
    __shared__ float att[128], h1s[128], fs[256], red[4];
    att[d] = attno[p * 128 + d];
    __syncthreads();
    float acc = 0.f;
    const float* wr = wo + d * 128;
    #pragma unroll 8
    for (int k = 0; k < 128; k++) acc = fmaf(wr[k], att[k], acc);
    float x = qf[p * 128 + d] + acc;
    // LN1
    float s = x;
    #pragma unroll
    for (int mask = 32; mask >= 1; mask >>= 1) s += __shfl_xor(s, mask);
    if ((d & 63) == 0) red[d >> 6] = s;
    __syncthreads();
    float mean = (red[0] + red[1]) * (1.f / 128.f);
    float dx = x - mean;
    float s2 = dx * dx;
    #pragma unroll
    for (int mask = 32; mask >= 1; mask >>= 1) s2 += __shfl_xor(s2, mask);
    if ((d & 63) == 0) red[2 + (d >> 6)] = s2;
    __syncthreads();
    float var = (red[2] + red[3]) * (1.f / 128.f);
    float h1v = dx * rsqrtf(var + 1e-5f) * ln1_g[d] + ln1_b[d];
    h1s[d] = h1v;
    __syncthreads();
    // FF1: j = d and j = d+128
    float a0 = 0.f, a1 = 0.f;
    const float* w1a = w_ff1 + d * 128;
    const float* w1b = w_ff1 + (d + 128) * 128;
    #pragma unroll 8
    for (int k = 0; k < 128; k++) {
        float hv = h1s[k];
        a0 = fmaf(w1a[k], hv, a0);
        a1 = fmaf(w1b[k], hv, a1);
    }
    fs[d] = fmaxf(a0 + b_ff1[d], 0.f);
    fs[d + 128] = fmaxf(a1 + b_ff1[d + 128], 0.f);
    __syncthreads();
    // FF2
    float a2 = 0.f;
    const float* w2 = w_ff2 + d * 256;
    #pragma unroll 8
    for (int j = 0; j < 256; j++) a2 = fmaf(w2[j], fs[j], a2);
    float x2 = h1v + a2 + b_ff2[d];
    // LN2
    __syncthreads();
    float t2 = x2;
    #pragma unroll
    for (int mask = 32; mask >= 1; mask >>= 1) t2 += __shfl_xor(t2, mask);
    if ((d & 63) == 0) red[d >> 6] = t2;
    __syncthreads();
    float mean2 = (red[0] + red[1]) * (1.f / 128.f);
    float dx2 = x2 - mean2;
    float v2 = dx2 * dx2;
    #pragma unroll
    for (int mask = 32; mask >= 1; mask >>= 1) v2 += __shfl_xor(v2, mask);
    if ((d & 63) == 0) red[2 + (d >> 6)] = v2;
    __syncthreads();
    float var2 = (red[2] + red[3]) * (1.f / 128.f);
    h2out[p * 128 + d] = dx2 * rsqrtf(var2 + 1e-5f) * ln2_g[d] + ln2_b[d];
}

// ---------------- prediction heads + score epilogue ----------------
__global__ void k_heads(const float* __restrict__ h2, const float* __restrict__ hm,
        const int* __restrict__ top_pos, const int* __restrict__ top_cls,
        const float* __restrict__ qpos,
        const float* __restrict__ w_hm, const float* __restrict__ b_hm,
        const float* __restrict__ w_rot, const float* __restrict__ b_rot,
        const float* __restrict__ w_dim, const float* __restrict__ b_dim,
        const float* __restrict__ w_center, const float* __restrict__ b_center,
        const float* __restrict__ w_height, const float* __restrict__ b_height,
        const float* __restrict__ w_vel, const float* __restrict__ b_vel,
        float* __restrict__ out) {
    int gid = blockIdx.x * 256 + threadIdx.x;
    if (gid >= 4000) return;
    int o = gid / 200, p = gid - o * 200;
    const float* wr; float bias;
    if (o < 10)      { wr = w_hm + o * 128;            bias = b_hm[o]; }
    else if (o < 12) { wr = w_rot + (o - 10) * 128;    bias = b_rot[o - 10]; }
    else if (o < 15) { wr = w_dim + (o - 12) * 128;    bias = b_dim[o - 12]; }
    else if (o < 17) { wr = w_center + (o - 15) * 128; bias = b_center[o - 15]; }
    else if (o < 18) { wr = w_height;                  bias = b_height[0]; }
    else             { wr = w_vel + (o - 18) * 128;    bias = b_vel[o - 18]; }
    const float* hr = h2 + p * 128;
    float dot = 0.f;
    #pragma unroll 8
    for (int d = 0; d < 128; d++) dot = fmaf(wr[d], hr[d], dot);
    dot += bias;
    float outv; int off;
    if (o < 10) {
        float qhs = hm[o * HWSZ + top_pos[p]];
        float oh = (top_cls[p] == o) ? 1.f : 0.f;
        outv = (1.f / (1.f + expf(-dot))) * qhs * oh;
        off = o * 200 + p;
    } else if (o < 12) { outv = dot; off = 2000 + (o - 10) * 200 + p; }
    else if (o < 15)   { outv = dot; off = 2400 + (o - 12) * 200 + p; }
    else if (o < 17)   { outv = dot + qpos[p * 2 + (o - 15)]; off = 3000 + (o - 15) * 200 + p; }
    else if (o < 18)   { outv = dot; off = 3400 + p; }
    else               { outv = dot; off = 3600 + (o - 18) * 200 + p; }
    out[off] = outv;
}

// ---------------- host ----------------
extern "C" void kernel_launch(void* const* d_in, const int* in_sizes, int n_in,
                              void* d_out, int out_size, void* d_ws, size_t ws_size,
                              hipStream_t stream) {
    const float* x        = (const float*)d_in[0];
    const float* w_shared = (const float*)d_in[1];
    const float* b_shared = (const float*)d_in[2];
    const float* w_heat   = (const float*)d_in[3];
    const float* b_heat   = (const float*)d_in[4];
    const float* w_ce     = (const float*)d_in[7];
    const float* b_ce     = (const float*)d_in[8];
    const float* w_qpos   = (const float*)d_in[9];
    const float* w_kpos   = (const float*)d_in[10];
    const float* wq       = (const float*)d_in[11];
    const float* wk       = (const float*)d_in[12];
    const float* wv       = (const float*)d_in[13];
    const float* wo       = (const float*)d_in[14];
    const float* ln1_g    = (const float*)d_in[15];
    const float* ln1_b    = (const float*)d_in[16];
    const float* ln2_g    = (const float*)d_in[17];
    const float* ln2_b    = (const float*)d_in[18];
    const float* w_ff1    = (const float*)d_in[19];
    const float* b_ff1    = (const float*)d_in[20];
    const float* w_ff2    = (const float*)d_in[21];
    const float* b_ff2    = (const float*)d_in[22];
    const float* w_center = (const float*)d_in[23];
    const float* b_center = (const float*)d_in[24];
    const float* w_height = (const float*)d_in[25];
    const float* b_height = (const float*)d_in[26];
    const float* w_dim    = (const float*)d_in[27];
    const float* b_dim    = (const float*)d_in[28];
    const float* w_rot    = (const float*)d_in[29];
    const float* b_rot    = (const float*)d_in[30];
    const float* w_vel    = (const float*)d_in[31];
    const float* b_vel    = (const float*)d_in[32];
    const float* w_hm     = (const float*)d_in[33];
    const float* b_hm     = (const float*)d_in[34];
    float* out = (float*)d_out;

    float* ws = (float*)d_ws;
    float* lidar = ws;                          // 2097152 f
    float* bigR  = lidar + 2097152;             // 8388608 f : xt_hi/xt_lo, later kvb/KpBh/VpBh
    ushort* xt_hi = (ushort*)bigR;              // 8388608 ushort
    ushort* xt_lo = xt_hi + 8388608;            // 8388608 ushort
    ushort* kvb  = (ushort*)bigR;               // bf16 [hw][128] (2097152 ush)
    ushort* KpBh = (ushort*)(bigR + 1048576);   // bf16 permuted K (2097152 ush)
    ushort* VpBh = (ushort*)(bigR + 2097152);   // bf16 permuted V (2097152 ush)
    float* wbh_f = bigR + 8388608;              // 294912 f
    float* wbl_f = wbh_f + 294912;              // 294912 f
    ushort* wb_hi = (ushort*)wbh_f;
    ushort* wb_lo = (ushort*)wbl_f;
    float* wt2   = wbl_f + 294912;              // 18432
    float* sig   = wt2 + 18432;                 // 163840
    float* hmb   = sig + 163840;                // 163840
    unsigned* hist_hi = (unsigned*)(hmb + 163840);   // 65536
    unsigned* hist_lo = hist_hi + 65536;        // 65536
    unsigned* state   = hist_lo + 65536;        // 64
    unsigned* cnts    = state + 64;             // 64
    unsigned* ck      = cnts + 64;              // 256
    unsigned* ci      = ck + 256;               // 256
    unsigned* ti      = ci + 256;               // 8192
    int* top_pos      = (int*)(ti + 8192);      // 256
    int* top_cls      = top_pos + 256;          // 256
    float* qpos  = (float*)(top_cls + 256);     // 512
    float* qf    = qpos + 512;                  // 25600
    float* qin   = qf + 25600;                  // 25600
    float* qbuf  = qin + 25600;                 // 25600
    float* attno = qbuf + 25600;                // 25600
    float* h2    = attno + 25600;               // 25600
    float* ps_b  = h2 + 25600;                  // 26624 (16*8*208)
    float* pacc_b = ps_b + 26624;               // 425984 (16*8*208*16)
    ushort* wkb  = (ushort*)(pacc_b + 425984);  // 16384 ush
    ushort* wvb  = wkb + 16384;                 // 16384 ush
    size_t needed = (size_t)((pacc_b + 425984 + 16384) - ws) * sizeof(float);
    if (ws_size < needed) return;

    k_prep_w2<<<72, 256, 0, stream>>>(w_heat, wt2);
    k_cvt_w<<<2304, 256, 0, stream>>>(w_shared, wb_hi, wb_lo);
    k_cvt_w128<<<64, 256, 0, stream>>>(wk, wv, wkb, wvb);
    k_cvt_x<<<dim3(256, 8), 256, 0, stream>>>(x, xt_hi, xt_lo);
    k_conv1_mfma<<<256, 256, 0, stream>>>(xt_hi, xt_lo, wb_hi, wb_lo, b_shared, lidar);
    k_conv2<<<256, 256, 0, stream>>>(lidar, wt2, b_heat, sig);
    hipMemsetAsync(hist_hi, 0, (65536u * 2 + 128) * sizeof(unsigned), stream);
    k_nms<<<640, 256, 0, stream>>>(sig, hmb, hist_hi);
    k_scan_hi<<<1, 256, 0, stream>>>(hist_hi, state);
    k_hist_lo<<<640, 256, 0, stream>>>(hmb, state, hist_lo);
    k_scan_lo<<<1, 256, 0, stream>>>(hist_lo, state);
    k_collect<<<640, 256, 0, stream>>>(hmb, state, ck, ci, ti, cnts);
    k_topk_final<<<1, 256, 0, stream>>>(state, cnts, ck, ci, ti, top_pos, top_cls);
    k_gather<<<100, 256, 0, stream>>>(lidar, top_pos, top_cls, w_ce, b_ce, w_qpos, qf, qin, qpos);
    k_kvin<<<256, 256, 0, stream>>>(lidar, w_kpos, kvb);
    k_gemm<0><<<dim3(4, 2), 256, 0, stream>>>(qin, wq, qbuf, 200, 128, 128, nullptr, nullptr);
    k_gemm_kv<<<256, 256, 0, stream>>>(kvb, wkb, KpBh);
    k_gemm_kv<<<256, 256, 0, stream>>>(kvb, wvb, VpBh);
    k_attn_part<<<dim3(13, 8, 16), 256, 0, stream>>>(qbuf, KpBh, VpBh, ps_b, pacc_b);
    k_attn_comb<<<200, 128, 0, stream>>>(ps_b, pacc_b, attno);
    k_tail<<<200, 128, 0, stream>>>(attno, qf, wo, ln1_g, ln1_b,
        w_ff1, b_ff1, w_ff2, b_ff2, ln2_g, ln2_b, h2);
    k_heads<<<16, 256, 0, stream>>>(h2, hmb, top_pos, top_cls, qpos,
        w_hm, b_hm, w_rot, b_rot, w_dim, b_dim, w_center, b_center,
        w_height, b_height, w_vel, b_vel, out);
}